// Round 9
// baseline (2835.050 us; speedup 1.0000x reference)
//
#include <hip/hip_runtime.h>
#include <hip/hip_bf16.h>

#define NN    38000
#define HID   128
#define RR    8
#define EE    200000
#define NROWS 60000
#define FF    19
#define NCLS  10

// width-dispatched integer read: wide=1 -> int64 storage, else int32
__device__ __forceinline__ int geti(const void* a, long long i, int wide){
  return wide ? (int)(((const long long*)a)[i]) : ((const int*)a)[i];
}

__global__ void k_fill(float* out, int n, float v){
  int i = blockIdx.x*256 + threadIdx.x;
  if (i < n) out[i] = v;
}

// flags[1]=mask repr (0=int32,1=bytes,2=bf16,3=f32,-1=?); flags[3]=edges int64; flags[4]=row_idx int64
__global__ void k_sniff(const void* mask, const void* ridx, const void* esrc, int* flags){
  if (blockIdx.x != 0 || threadIdx.x != 0) return;
  const unsigned short* mu = (const unsigned short*)mask;
  int n3f80e = 0, n3f80o = 0, nbytehi = 0, noddnz = 0, nother = 0;
  for (int i = 0; i < 4096; i++){
    unsigned v = mu[i];
    if (v == 0) continue;
    if (v == 0x3F80){ if (i & 1) n3f80o++; else n3f80e++; continue; }
    unsigned lo = v & 0xFF, hi = v >> 8;
    int lob = (lo == 0 || lo == 1 || lo == 0xFF);
    int hib = (hi == 0 || hi == 1 || hi == 0xFF);
    if (lob && hib){ if (hi) nbytehi++; if (i & 1) noddnz++; continue; }
    nother++;
  }
  int mtype = -1;
  if (nother == 0){
    if (n3f80e > 0 && nbytehi == 0 && noddnz == 0)      mtype = 2;
    else if (n3f80o > 0 && n3f80e == 0 && nbytehi == 0) mtype = 3;
    else if (n3f80e + n3f80o == 0){
      if (nbytehi > 0 || noddnz > 0) mtype = 1;
      else                           mtype = 0;
    }
  }
  flags[1] = mtype;
  const int* es = (const int*)esrc;
  int wE = 1, seenE = 0;
  for (int i = 0; i < 512; i++){
    if (es[2*i+1] != 0){ wE = 0; break; }
    if (es[2*i] > 1) seenE = 1;
  }
  flags[3] = (wE && seenE) ? 1 : 0;
  const int* ri = (const int*)ridx;
  int wI = 1, seenI = 0;
  for (int i = 0; i < 512; i++){
    if (ri[2*i+1] != 0){ wI = 0; break; }
    if (ri[2*i] > 1) seenI = 1;
  }
  flags[4] = (wI && seenI) ? 1 : 0;
}

__global__ void k_init(int* head, float* cs, float* cd){
  int i = blockIdx.x*256 + threadIdx.x;
  if (i >= RR*NN) return;
  head[i] = -1; cs[i] = 0.f; cd[i] = 0.f;
}

__global__ void k_graph(const void* src, const void* dst,
                        float* cs, float* cd, int* head, int* nxt,
                        const int* flags){
  int i = blockIdx.x*256 + threadIdx.x;
  if (i >= RR*EE) return;
  int wide = flags[3];
  int r = i / EE;
  int s = geti(src, i, wide);
  int d = geti(dst, i, wide);
  atomicAdd(cs + r*NN + s, 1.0f);
  int dd = r*NN + d;
  atomicAdd(cd + dd, 1.0f);
  nxt[i] = atomicExch(head + dd, i);
}

__global__ void k_norm(float* cs, float* cd){
  int i = blockIdx.x*256 + threadIdx.x;
  if (i >= RR*NN) return;
  float a = cs[i]; cs[i] = rsqrtf(a > 0.f ? a : 1.f);
  float b = cd[i]; cd[i] = rsqrtf(b > 0.f ? b : 1.f);
}

// one relation's aggregation via linked list (no atomics), all f32
__global__ void k_agg_r(const float* h, const void* src, const int* head_r,
                        const int* nxt, const float* ns_r, const float* nd_r,
                        float* agg, const int* flags){
  int d = blockIdx.x;
  int f = threadIdx.x;
  int wide = flags[3];
  float acc = 0.f;
  int e = head_r[d];
  while (e >= 0){
    int s  = geti(src, e, wide);
    int en = nxt[e];
    acc += ns_r[s] * h[(long long)s*HID + f];
    e = en;
  }
  agg[(long long)d*HID + f] = acc * nd_r[d];
}

// C[M][128] (init? = : +=) A[M][128] @ B[128][128], all f32
__global__ void k_gemm_acc(const float* A, const float* B, float* C, int init){
  int row0 = blockIdx.x * 4;
  int col  = threadIdx.x;
  float a0=0.f, a1=0.f, a2=0.f, a3=0.f;
  for (int k = 0; k < HID; k++){
    float bv = B[k*HID + col];
    a0 += A[(long long)(row0+0)*HID + k] * bv;
    a1 += A[(long long)(row0+1)*HID + k] * bv;
    a2 += A[(long long)(row0+2)*HID + k] * bv;
    a3 += A[(long long)(row0+3)*HID + k] * bv;
  }
  long long o = (long long)row0*HID + col;
  if (init){ C[o]=a0; C[o+HID]=a1; C[o+2*HID]=a2; C[o+3*HID]=a3; }
  else     { C[o]+=a0; C[o+HID]+=a1; C[o+2*HID]+=a2; C[o+3*HID]+=a3; }
}

__global__ void k_finish(const float* hacc, const float* bias, float* h, int relu){
  long long i = (long long)blockIdx.x*256 + threadIdx.x;
  if (i >= (long long)NN*HID) return;
  float x = hacc[i] + bias[(int)(i & 127)];
  if (relu) x = fmaxf(x, 0.f);
  h[i] = x;
}

// biases (f32): [b_in | sum_r b1 | sum_r b2 | bm1 | bm2 | bm3]
__global__ void k_bias(const float* b_in, const float* b1, const float* b2,
                       const float* bm1, const float* bm2, const float* bm3, float* o){
  int t = threadIdx.x;
  o[t] = b_in[t];
  float s1 = 0.f, s2 = 0.f;
  for (int r = 0; r < RR; r++){ s1 += b1[r*HID+t]; s2 += b2[r*HID+t]; }
  o[128+t] = s1; o[256+t] = s2;
  o[384+t] = bm1[t]; o[512+t] = bm2[t];
  if (t < NCLS) o[640+t] = bm3[t];
}

// plain f32 GEMM: out[M][Ncols] = maybe-relu(A[M][K] @ B[K][N] + bias)
__global__ void k_gemm(const float* A, const float* B, const float* bias, float* out,
                       int M, int K, int N, int Ncols, int relu){
  int row0 = blockIdx.x * 4;
  if (row0 >= M) return;
  int col = threadIdx.x;
  float a0=0.f, a1=0.f, a2=0.f, a3=0.f;
  for (int k = 0; k < K; k++){
    float bv = (col < N) ? B[(long long)k*N + col] : 0.f;
    a0 += A[(long long)(row0+0)*K + k] * bv;
    a1 += A[(long long)(row0+1)*K + k] * bv;
    a2 += A[(long long)(row0+2)*K + k] * bv;
    a3 += A[(long long)(row0+3)*K + k] * bv;
  }
  if (col < Ncols){
    float bb = bias[col];
    float x;
    x = a0 + bb; if (relu) x = fmaxf(x, 0.f); out[(long long)(row0+0)*Ncols + col] = x;
    x = a1 + bb; if (relu) x = fmaxf(x, 0.f); out[(long long)(row0+1)*Ncols + col] = x;
    x = a2 + bb; if (relu) x = fmaxf(x, 0.f); out[(long long)(row0+2)*Ncols + col] = x;
    x = a3 + bb; if (relu) x = fmaxf(x, 0.f); out[(long long)(row0+3)*Ncols + col] = x;
  }
}

// ragged gather + masked mean; mask repr flags[1], index width flags[4]
__global__ void k_mean(const float* h, const void* ridx, const void* rmask,
                       const int* flags, float* mean){
  int row = blockIdx.x;
  int f = threadIdx.x;
  int mt = flags[1];
  int wide = flags[4];
  const int* m4            = (const int*)rmask;
  const unsigned char* m1  = (const unsigned char*)rmask;
  const unsigned short* m2 = (const unsigned short*)rmask;
  const unsigned int* mw   = (const unsigned int*)rmask;
  float acc = 0.f, cnt = 0.f;
  for (int j = 0; j < FF; j++){
    int i = row*FF + j;
    int on;
    if      (mt == 1) on = (m1[i] != 0);
    else if (mt == 2) on = (m2[i] != 0);
    else if (mt == 3) on = (mw[i] != 0);
    else              on = (m4[i] != 0);
    if (on){
      int idx = geti(ridx, i, wide);
      acc += h[(long long)idx*HID + f];
      cnt += 1.f;
    }
  }
  mean[(long long)row*HID + f] = acc / fmaxf(cnt, 1.f);
}

extern "C" void kernel_launch(void* const* d_in, const int* in_sizes, int n_in,
                              void* d_out, int out_size, void* d_ws, size_t ws_size,
                              hipStream_t stream){
  float* out = (float*)d_out;   // f32 output (proven round 8)

  static const int expect[17] = {
    NN*64, RR*EE, RR*EE, NROWS*FF, NROWS*FF,
    64*HID, HID, RR*HID*HID, RR*HID, RR*HID*HID, RR*HID,
    HID*HID, HID, HID*HID, HID, HID*NCLS, NCLS };
  bool ok = (n_in >= 17) && (out_size == NROWS*NCLS);
  if (ok) for (int i = 0; i < 17; i++) if (in_sizes[i] != expect[i]) { ok = false; break; }
  if (!ok){
    k_fill<<<(NROWS*NCLS+255)/256, 256, 0, stream>>>(out, NROWS*NCLS, 64.0f);
    return;
  }

  const void*  e_src = d_in[1];
  const void*  e_dst = d_in[2];
  const void*  ridx  = d_in[3];
  const void*  rmask = d_in[4];
  const float* nf    = (const float*)d_in[0];
  const float* W_in  = (const float*)d_in[5];
  const float* b_in  = (const float*)d_in[6];
  const float* W1    = (const float*)d_in[7];
  const float* b1    = (const float*)d_in[8];
  const float* W2    = (const float*)d_in[9];
  const float* b2    = (const float*)d_in[10];
  const float* Wm1   = (const float*)d_in[11];
  const float* bm1   = (const float*)d_in[12];
  const float* Wm2   = (const float*)d_in[13];
  const float* bm2   = (const float*)d_in[14];
  const float* Wm3   = (const float*)d_in[15];
  const float* bm3   = (const float*)d_in[16];

  char* ws = (char*)d_ws;
  size_t off = 0;
  auto take = [&](size_t bytes)->char*{
    char* p = ws + off; off += (bytes + 255) & ~(size_t)255; return p; };

  int*   flags = (int*)  take(256);
  char*  rgnB  =         take(40894464);            // 39 MiB
  float* hacc  = (float*)(rgnB);                    // graph phase (19.456 MB)
  float* aggf  = (float*)(rgnB + 19456000);         // graph phase (19.456 MB)
  float* meanb = (float*)(rgnB);                    // MLP: mean, then x2 (30.72 MB)
  float* h1    = (float*)take((size_t)NN*HID*4);    // 19.456 MB
  float* h2    = (float*)take((size_t)NN*HID*4);    // 19.456 MB (contiguous after h1)
  float* x1    = (float*)h1;                        // MLP: 30.72 MB spans h1+h2 (dead then)
  int*   head  = (int*)  take((size_t)RR*NN*4);
  int*   nxt   = (int*)  take((size_t)RR*EE*4);
  float* ns    = (float*)take((size_t)RR*NN*4);
  float* nd    = (float*)take((size_t)RR*NN*4);
  float* bias  = (float*)take(656*4);

  if (off > ws_size){
    k_fill<<<(NROWS*NCLS+255)/256, 256, 0, stream>>>(out, NROWS*NCLS, 32.0f);
    return;
  }

  k_sniff<<<1, 1, 0, stream>>>(rmask, ridx, e_src, flags);
  k_init <<<(RR*NN+255)/256, 256, 0, stream>>>(head, ns, nd);
  k_graph<<<(RR*EE+255)/256, 256, 0, stream>>>(e_src, e_dst, ns, nd, head, nxt, flags);
  k_norm <<<(RR*NN+255)/256, 256, 0, stream>>>(ns, nd);
  k_bias <<<1, 128, 0, stream>>>(b_in, b1, b2, bm1, bm2, bm3, bias);

  // input linear + relu: h1 = relu(nf @ W_in + b_in)
  k_gemm<<<NN/4, 128, 0, stream>>>(nf, W_in, bias+0, h1, NN, 64, HID, HID, 1);

  // RGCN layer 1 (relu)
  for (int r = 0; r < RR; r++){
    k_agg_r   <<<NN, 128, 0, stream>>>(h1, e_src, head + r*NN, nxt,
                                       ns + r*NN, nd + r*NN, aggf, flags);
    k_gemm_acc<<<NN/4, 128, 0, stream>>>(aggf, W1 + r*HID*HID, hacc, r == 0);
  }
  k_finish<<<(NN*HID+255)/256, 256, 0, stream>>>(hacc, bias+128, h2, 1);

  // RGCN layer 2 (no relu)
  for (int r = 0; r < RR; r++){
    k_agg_r   <<<NN, 128, 0, stream>>>(h2, e_src, head + r*NN, nxt,
                                       ns + r*NN, nd + r*NN, aggf, flags);
    k_gemm_acc<<<NN/4, 128, 0, stream>>>(aggf, W2 + r*HID*HID, hacc, r == 0);
  }
  k_finish<<<(NN*HID+255)/256, 256, 0, stream>>>(hacc, bias+256, h1, 0);

  // masked mean: mean(rgnB) <- gather(h1)   [hacc/aggf dead]
  k_mean<<<NROWS, 128, 0, stream>>>(h1, ridx, rmask, flags, meanb);

  // MLP head (f32): mean(rgnB) -> x1(h1+h2) -> x2(rgnB) -> out
  k_gemm<<<NROWS/4, 128, 0, stream>>>(meanb, Wm1, bias+384, x1,   NROWS, HID, HID, HID, 1);
  k_gemm<<<NROWS/4, 128, 0, stream>>>(x1,    Wm2, bias+512, meanb, NROWS, HID, HID, HID, 1);
  k_gemm<<<NROWS/4, 128, 0, stream>>>(meanb, Wm3, bias+640, out,  NROWS, HID, NCLS, NCLS, 0);
}

// Round 12
// 2353.276 us; speedup vs baseline: 1.2047x; 1.2047x over previous
//
#include <hip/hip_runtime.h>
#include <hip/hip_bf16.h>

#define NN    38000
#define HID   128
#define RR    8
#define EE    200000
#define NROWS 60000
#define FF    19
#define NCLS  10

// width-dispatched integer read: wide=1 -> int64 storage, else int32
__device__ __forceinline__ int geti(const void* a, long long i, int wide){
  return wide ? (int)(((const long long*)a)[i]) : ((const int*)a)[i];
}

__global__ void k_fill(float* out, int n, float v){
  int i = blockIdx.x*256 + threadIdx.x;
  if (i < n) out[i] = v;
}

// flags[1]=mask repr (0=int32,1=bytes,2=bf16,3=f32,-1=?); flags[3]=edges int64; flags[4]=row_idx int64
// Parallel (1 wave) version of r9's serial sniff — identical flag semantics:
// the decision logic only consumes existence predicates, and the original's
// early-break terms are ANDed away whenever the break fires.
__global__ void k_sniff(const void* mask, const void* ridx, const void* esrc, int* flags){
  int lane = threadIdx.x;    // blockDim = 64, one wave
  const unsigned short* mu = (const unsigned short*)mask;
  int l3f80e=0, l3f80o=0, lbytehi=0, loddnz=0, lother=0;
  for (int i = lane; i < 4096; i += 64){
    unsigned v = mu[i];
    if (v == 0) continue;
    if (v == 0x3F80){ if (i & 1) l3f80o = 1; else l3f80e = 1; continue; }
    unsigned lo = v & 0xFF, hi = v >> 8;
    int lob = (lo == 0 || lo == 1 || lo == 0xFF);
    int hib = (hi == 0 || hi == 1 || hi == 0xFF);
    if (lob && hib){ if (hi) lbytehi = 1; if (i & 1) loddnz = 1; continue; }
    lother = 1;
  }
  int a3f80e = __any(l3f80e);
  int a3f80o = __any(l3f80o);
  int abytehi = __any(lbytehi);
  int aoddnz = __any(loddnz);
  int aother = __any(lother);
  int mtype = -1;
  if (!aother){
    if (a3f80e && !abytehi && !aoddnz)       mtype = 2;
    else if (a3f80o && !a3f80e && !abytehi)  mtype = 3;
    else if (!a3f80e && !a3f80o){
      if (abytehi || aoddnz) mtype = 1;
      else                   mtype = 0;
    }
  }
  const int* es = (const int*)esrc;
  int loddE = 0, lseenE = 0;
  for (int i = lane; i < 512; i += 64){
    if (es[2*i+1] != 0) loddE = 1;
    if (es[2*i] > 1)    lseenE = 1;
  }
  int fE = (!__any(loddE) && __any(lseenE)) ? 1 : 0;
  const int* ri = (const int*)ridx;
  int loddI = 0, lseenI = 0;
  for (int i = lane; i < 512; i += 64){
    if (ri[2*i+1] != 0) loddI = 1;
    if (ri[2*i] > 1)    lseenI = 1;
  }
  int fI = (!__any(loddI) && __any(lseenI)) ? 1 : 0;
  if (lane == 0){
    flags[1] = mtype;
    flags[3] = fE;
    flags[4] = fI;
  }
}

__global__ void k_init(int* head, float* cs, float* cd){
  int i = blockIdx.x*256 + threadIdx.x;
  if (i >= RR*NN) return;
  head[i] = -1; cs[i] = 0.f; cd[i] = 0.f;
}

__global__ void k_graph(const void* src, const void* dst,
                        float* cs, float* cd, int* head, int* nxt,
                        const int* flags){
  int i = blockIdx.x*256 + threadIdx.x;
  if (i >= RR*EE) return;
  int wide = flags[3];
  int r = i / EE;
  int s = geti(src, i, wide);
  int d = geti(dst, i, wide);
  atomicAdd(cs + r*NN + s, 1.0f);
  int dd = r*NN + d;
  atomicAdd(cd + dd, 1.0f);
  nxt[i] = atomicExch(head + dd, i);
}

__global__ void k_norm(float* cs, float* cd){
  int i = blockIdx.x*256 + threadIdx.x;
  if (i >= RR*NN) return;
  float a = cs[i]; cs[i] = rsqrtf(a > 0.f ? a : 1.f);
  float b = cd[i]; cd[i] = rsqrtf(b > 0.f ? b : 1.f);
}

// one relation's aggregation via linked list (no atomics), all f32
__global__ void k_agg_r(const float* h, const void* src, const int* head_r,
                        const int* nxt, const float* ns_r, const float* nd_r,
                        float* agg, const int* flags){
  int d = blockIdx.x;
  int f = threadIdx.x;
  int wide = flags[3];
  float acc = 0.f;
  int e = head_r[d];
  while (e >= 0){
    int s  = geti(src, e, wide);
    int en = nxt[e];
    acc += ns_r[s] * h[(long long)s*HID + f];
    e = en;
  }
  agg[(long long)d*HID + f] = acc * nd_r[d];
}

// C[M][128] (init? = : +=) A[M][128] @ B[128][128], all f32
__global__ void k_gemm_acc(const float* A, const float* B, float* C, int init){
  int row0 = blockIdx.x * 4;
  int col  = threadIdx.x;
  float a0=0.f, a1=0.f, a2=0.f, a3=0.f;
  for (int k = 0; k < HID; k++){
    float bv = B[k*HID + col];
    a0 += A[(long long)(row0+0)*HID + k] * bv;
    a1 += A[(long long)(row0+1)*HID + k] * bv;
    a2 += A[(long long)(row0+2)*HID + k] * bv;
    a3 += A[(long long)(row0+3)*HID + k] * bv;
  }
  long long o = (long long)row0*HID + col;
  if (init){ C[o]=a0; C[o+HID]=a1; C[o+2*HID]=a2; C[o+3*HID]=a3; }
  else     { C[o]+=a0; C[o+HID]+=a1; C[o+2*HID]+=a2; C[o+3*HID]+=a3; }
}

__global__ void k_finish(const float* hacc, const float* bias, float* h, int relu){
  long long i = (long long)blockIdx.x*256 + threadIdx.x;
  if (i >= (long long)NN*HID) return;
  float x = hacc[i] + bias[(int)(i & 127)];
  if (relu) x = fmaxf(x, 0.f);
  h[i] = x;
}

// biases (f32): [b_in | sum_r b1 | sum_r b2 | bm1 | bm2 | bm3]
__global__ void k_bias(const float* b_in, const float* b1, const float* b2,
                       const float* bm1, const float* bm2, const float* bm3, float* o){
  int t = threadIdx.x;
  o[t] = b_in[t];
  float s1 = 0.f, s2 = 0.f;
  for (int r = 0; r < RR; r++){ s1 += b1[r*HID+t]; s2 += b2[r*HID+t]; }
  o[128+t] = s1; o[256+t] = s2;
  o[384+t] = bm1[t]; o[512+t] = bm2[t];
  if (t < NCLS) o[640+t] = bm3[t];
}

// plain f32 GEMM: out[M][Ncols] = maybe-relu(A[M][K] @ B[K][N] + bias)
__global__ void k_gemm(const float* A, const float* B, const float* bias, float* out,
                       int M, int K, int N, int Ncols, int relu){
  int row0 = blockIdx.x * 4;
  if (row0 >= M) return;
  int col = threadIdx.x;
  float a0=0.f, a1=0.f, a2=0.f, a3=0.f;
  for (int k = 0; k < K; k++){
    float bv = (col < N) ? B[(long long)k*N + col] : 0.f;
    a0 += A[(long long)(row0+0)*K + k] * bv;
    a1 += A[(long long)(row0+1)*K + k] * bv;
    a2 += A[(long long)(row0+2)*K + k] * bv;
    a3 += A[(long long)(row0+3)*K + k] * bv;
  }
  if (col < Ncols){
    float bb = bias[col];
    float x;
    x = a0 + bb; if (relu) x = fmaxf(x, 0.f); out[(long long)(row0+0)*Ncols + col] = x;
    x = a1 + bb; if (relu) x = fmaxf(x, 0.f); out[(long long)(row0+1)*Ncols + col] = x;
    x = a2 + bb; if (relu) x = fmaxf(x, 0.f); out[(long long)(row0+2)*Ncols + col] = x;
    x = a3 + bb; if (relu) x = fmaxf(x, 0.f); out[(long long)(row0+3)*Ncols + col] = x;
  }
}

// ragged gather + masked mean; mask repr flags[1], index width flags[4]
__global__ void k_mean(const float* h, const void* ridx, const void* rmask,
                       const int* flags, float* mean){
  int row = blockIdx.x;
  int f = threadIdx.x;
  int mt = flags[1];
  int wide = flags[4];
  const int* m4            = (const int*)rmask;
  const unsigned char* m1  = (const unsigned char*)rmask;
  const unsigned short* m2 = (const unsigned short*)rmask;
  const unsigned int* mw   = (const unsigned int*)rmask;
  float acc = 0.f, cnt = 0.f;
  for (int j = 0; j < FF; j++){
    int i = row*FF + j;
    int on;
    if      (mt == 1) on = (m1[i] != 0);
    else if (mt == 2) on = (m2[i] != 0);
    else if (mt == 3) on = (mw[i] != 0);
    else              on = (m4[i] != 0);
    if (on){
      int idx = geti(ridx, i, wide);
      acc += h[(long long)idx*HID + f];
      cnt += 1.f;
    }
  }
  mean[(long long)row*HID + f] = acc / fmaxf(cnt, 1.f);
}

extern "C" void kernel_launch(void* const* d_in, const int* in_sizes, int n_in,
                              void* d_out, int out_size, void* d_ws, size_t ws_size,
                              hipStream_t stream){
  float* out = (float*)d_out;   // f32 output (proven round 8/9)

  static const int expect[17] = {
    NN*64, RR*EE, RR*EE, NROWS*FF, NROWS*FF,
    64*HID, HID, RR*HID*HID, RR*HID, RR*HID*HID, RR*HID,
    HID*HID, HID, HID*HID, HID, HID*NCLS, NCLS };
  bool ok = (n_in >= 17) && (out_size == NROWS*NCLS);
  if (ok) for (int i = 0; i < 17; i++) if (in_sizes[i] != expect[i]) { ok = false; break; }
  if (!ok){
    k_fill<<<(NROWS*NCLS+255)/256, 256, 0, stream>>>(out, NROWS*NCLS, 64.0f);
    return;
  }

  const void*  e_src = d_in[1];
  const void*  e_dst = d_in[2];
  const void*  ridx  = d_in[3];
  const void*  rmask = d_in[4];
  const float* nf    = (const float*)d_in[0];
  const float* W_in  = (const float*)d_in[5];
  const float* b_in  = (const float*)d_in[6];
  const float* W1    = (const float*)d_in[7];
  const float* b1    = (const float*)d_in[8];
  const float* W2    = (const float*)d_in[9];
  const float* b2    = (const float*)d_in[10];
  const float* Wm1   = (const float*)d_in[11];
  const float* bm1   = (const float*)d_in[12];
  const float* Wm2   = (const float*)d_in[13];
  const float* bm2   = (const float*)d_in[14];
  const float* Wm3   = (const float*)d_in[15];
  const float* bm3   = (const float*)d_in[16];

  char* ws = (char*)d_ws;
  size_t off = 0;
  auto take = [&](size_t bytes)->char*{
    char* p = ws + off; off += (bytes + 255) & ~(size_t)255; return p; };

  int*   flags = (int*)  take(256);
  char*  rgnB  =         take(40894464);            // 39 MiB
  float* hacc  = (float*)(rgnB);                    // graph phase (19.456 MB)
  float* aggf  = (float*)(rgnB + 19456000);         // graph phase (19.456 MB)
  float* meanb = (float*)(rgnB);                    // MLP: mean, then x2 (30.72 MB)
  float* h1    = (float*)take((size_t)NN*HID*4);    // 19.456 MB
  float* h2    = (float*)take((size_t)NN*HID*4);    // 19.456 MB (contiguous after h1)
  float* x1    = (float*)h1;                        // MLP: 30.72 MB spans h1+h2 (dead then)
  int*   head  = (int*)  take((size_t)RR*NN*4);
  int*   nxt   = (int*)  take((size_t)RR*EE*4);
  float* ns    = (float*)take((size_t)RR*NN*4);
  float* nd    = (float*)take((size_t)RR*NN*4);
  float* bias  = (float*)take(656*4);

  if (off > ws_size){
    k_fill<<<(NROWS*NCLS+255)/256, 256, 0, stream>>>(out, NROWS*NCLS, 32.0f);
    return;
  }

  k_sniff<<<1, 64, 0, stream>>>(rmask, ridx, e_src, flags);
  k_init <<<(RR*NN+255)/256, 256, 0, stream>>>(head, ns, nd);
  k_graph<<<(RR*EE+255)/256, 256, 0, stream>>>(e_src, e_dst, ns, nd, head, nxt, flags);
  k_norm <<<(RR*NN+255)/256, 256, 0, stream>>>(ns, nd);
  k_bias <<<1, 128, 0, stream>>>(b_in, b1, b2, bm1, bm2, bm3, bias);

  // input linear + relu: h1 = relu(nf @ W_in + b_in)
  k_gemm<<<NN/4, 128, 0, stream>>>(nf, W_in, bias+0, h1, NN, 64, HID, HID, 1);

  // RGCN layer 1 (relu)
  for (int r = 0; r < RR; r++){
    k_agg_r   <<<NN, 128, 0, stream>>>(h1, e_src, head + r*NN, nxt,
                                       ns + r*NN, nd + r*NN, aggf, flags);
    k_gemm_acc<<<NN/4, 128, 0, stream>>>(aggf, W1 + r*HID*HID, hacc, r == 0);
  }
  k_finish<<<(NN*HID+255)/256, 256, 0, stream>>>(hacc, bias+128, h2, 1);

  // RGCN layer 2 (no relu)
  for (int r = 0; r < RR; r++){
    k_agg_r   <<<NN, 128, 0, stream>>>(h2, e_src, head + r*NN, nxt,
                                       ns + r*NN, nd + r*NN, aggf, flags);
    k_gemm_acc<<<NN/4, 128, 0, stream>>>(aggf, W2 + r*HID*HID, hacc, r == 0);
  }
  k_finish<<<(NN*HID+255)/256, 256, 0, stream>>>(hacc, bias+256, h1, 0);

  // masked mean: mean(rgnB) <- gather(h1)   [hacc/aggf dead]
  k_mean<<<NROWS, 128, 0, stream>>>(h1, ridx, rmask, flags, meanb);

  // MLP head (f32): mean(rgnB) -> x1(h1+h2) -> x2(rgnB) -> out
  k_gemm<<<NROWS/4, 128, 0, stream>>>(meanb, Wm1, bias+384, x1,   NROWS, HID, HID, HID, 1);
  k_gemm<<<NROWS/4, 128, 0, stream>>>(x1,    Wm2, bias+512, meanb, NROWS, HID, HID, HID, 1);
  k_gemm<<<NROWS/4, 128, 0, stream>>>(meanb, Wm3, bias+640, out,  NROWS, HID, NCLS, NCLS, 0);
}

// Round 13
// 1404.771 us; speedup vs baseline: 2.0182x; 1.6752x over previous
//
#include <hip/hip_runtime.h>
#include <hip/hip_bf16.h>

#define NN    38000
#define HID   128
#define RR    8
#define EE    200000
#define NROWS 60000
#define FF    19
#define NCLS  10

typedef __hip_bfloat16 bf16;
typedef __attribute__((ext_vector_type(8))) short short8;
typedef __attribute__((ext_vector_type(4))) float floatx4;

__device__ __forceinline__ float b2f(bf16 x){ return __bfloat162float(x); }
__device__ __forceinline__ bf16  f2b(float x){ return __float2bfloat16(x); }

__device__ __forceinline__ int geti(const void* a, long long i, int wide){
  return wide ? (int)(((const long long*)a)[i]) : ((const int*)a)[i];
}

__global__ void k_fill(float* out, int n, float v){
  int i = blockIdx.x*256 + threadIdx.x;
  if (i < n) out[i] = v;
}

// r12's proven parallel sniff (1 wave), identical flag semantics
__global__ void k_sniff(const void* mask, const void* ridx, const void* esrc, int* flags){
  int lane = threadIdx.x;    // blockDim = 64
  const unsigned short* mu = (const unsigned short*)mask;
  int l3f80e=0, l3f80o=0, lbytehi=0, loddnz=0, lother=0;
  for (int i = lane; i < 4096; i += 64){
    unsigned v = mu[i];
    if (v == 0) continue;
    if (v == 0x3F80){ if (i & 1) l3f80o = 1; else l3f80e = 1; continue; }
    unsigned lo = v & 0xFF, hi = v >> 8;
    int lob = (lo == 0 || lo == 1 || lo == 0xFF);
    int hib = (hi == 0 || hi == 1 || hi == 0xFF);
    if (lob && hib){ if (hi) lbytehi = 1; if (i & 1) loddnz = 1; continue; }
    lother = 1;
  }
  int a3f80e = __any(l3f80e);
  int a3f80o = __any(l3f80o);
  int abytehi = __any(lbytehi);
  int aoddnz = __any(loddnz);
  int aother = __any(lother);
  int mtype = -1;
  if (!aother){
    if (a3f80e && !abytehi && !aoddnz)       mtype = 2;
    else if (a3f80o && !a3f80e && !abytehi)  mtype = 3;
    else if (!a3f80e && !a3f80o){
      if (abytehi || aoddnz) mtype = 1;
      else                   mtype = 0;     // int32 0/1 (the actual runtime case)
    }
  }
  const int* es = (const int*)esrc;
  int loddE = 0, lseenE = 0;
  for (int i = lane; i < 512; i += 64){
    if (es[2*i+1] != 0) loddE = 1;
    if (es[2*i] > 1)    lseenE = 1;
  }
  int fE = (!__any(loddE) && __any(lseenE)) ? 1 : 0;
  const int* ri = (const int*)ridx;
  int loddI = 0, lseenI = 0;
  for (int i = lane; i < 512; i += 64){
    if (ri[2*i+1] != 0) loddI = 1;
    if (ri[2*i] > 1)    lseenI = 1;
  }
  int fI = (!__any(loddI) && __any(lseenI)) ? 1 : 0;
  if (lane == 0){ flags[1] = mtype; flags[3] = fE; flags[4] = fI; }
}

__global__ void k_init(int* head, float* cs, float* cd){
  int i = blockIdx.x*256 + threadIdx.x;
  if (i >= RR*NN) return;
  head[i] = -1; cs[i] = 0.f; cd[i] = 0.f;
}

__global__ void k_graph(const void* src, const void* dst,
                        float* cs, float* cd, int* head, int* nxt, const int* flags){
  int i = blockIdx.x*256 + threadIdx.x;
  if (i >= RR*EE) return;
  int wide = flags[3];
  int r = i / EE;
  int s = geti(src, i, wide);
  int d = geti(dst, i, wide);
  atomicAdd(cs + r*NN + s, 1.0f);
  int dd = r*NN + d;
  atomicAdd(cd + dd, 1.0f);
  nxt[i] = atomicExch(head + dd, i);
}

__global__ void k_norm(float* cs, float* cd){
  int i = blockIdx.x*256 + threadIdx.x;
  if (i >= RR*NN) return;
  float a = cs[i]; cs[i] = rsqrtf(a > 0.f ? a : 1.f);
  float b = cd[i]; cd[i] = rsqrtf(b > 0.f ? b : 1.f);
}

__global__ void k_bias(const float* b_in, const float* b1, const float* b2,
                       const float* bm1, const float* bm2, const float* bm3, float* o){
  int t = threadIdx.x;
  o[t] = b_in[t];
  float s1 = 0.f, s2 = 0.f;
  for (int r = 0; r < RR; r++){ s1 += b1[r*HID+t]; s2 += b2[r*HID+t]; }
  o[128+t] = s1; o[256+t] = s2;
  o[384+t] = bm1[t]; o[512+t] = bm2[t];
  if (t < NCLS) o[640+t] = bm3[t];
}

// pack f32 [batch][128][128] weights into MFMA B-fragment order (bf16)
// elem j of lane l, tile (nt,kt): B[kt*32+(l>>4)*8+j][nt*16+(l&15)]
__global__ void k_pack(const float* __restrict__ B, bf16* __restrict__ out, int total){
  int idx = blockIdx.x*256 + threadIdx.x;
  if (idx >= total) return;
  int j  = idx & 7;
  int l  = (idx >> 3) & 63;
  int t  = (idx >> 9) & 31;
  int r  = idx >> 14;
  int kt = t & 3;
  int nt = t >> 2;
  int k = kt*32 + ((l>>4)<<3) + j;
  int n = nt*16 + (l&15);
  out[idx] = f2b(B[r*16384 + k*128 + n]);
}

// input linear + relu (f32 VALU, K=64) -> h1 bf16
__global__ void k_gemm_in(const float* __restrict__ A, const float* __restrict__ B,
                          const float* bias, bf16* __restrict__ out){
  int row0 = blockIdx.x * 4;
  int col = threadIdx.x;
  float a0=0.f, a1=0.f, a2=0.f, a3=0.f;
  for (int k = 0; k < 64; k++){
    float bv = B[k*HID + col];
    a0 += A[(long long)(row0+0)*64 + k] * bv;
    a1 += A[(long long)(row0+1)*64 + k] * bv;
    a2 += A[(long long)(row0+2)*64 + k] * bv;
    a3 += A[(long long)(row0+3)*64 + k] * bv;
  }
  float bb = bias[col];
  out[(long long)(row0+0)*HID + col] = f2b(fmaxf(a0 + bb, 0.f));
  out[(long long)(row0+1)*HID + col] = f2b(fmaxf(a1 + bb, 0.f));
  out[(long long)(row0+2)*HID + col] = f2b(fmaxf(a2 + bb, 0.f));
  out[(long long)(row0+3)*HID + col] = f2b(fmaxf(a3 + bb, 0.f));
}

// one relation's aggregation; bf16 h gathers, bf16 agg out
__global__ void k_agg_r(const bf16* __restrict__ h, const void* src,
                        const int* __restrict__ head_r, const int* __restrict__ nxt,
                        const float* __restrict__ ns_r, const float* __restrict__ nd_r,
                        bf16* __restrict__ agg, const int* flags){
  int d = blockIdx.x;
  int f = threadIdx.x;
  int wide = flags[3];
  float acc = 0.f;
  int e = head_r[d];
  while (e >= 0){
    int s  = geti(src, e, wide);
    int en = nxt[e];
    acc += ns_r[s] * b2f(h[(long long)s*HID + f]);
    e = en;
  }
  agg[(long long)d*HID + f] = f2b(acc * nd_r[d]);
}

// MFMA GEMM: C(f32)[M][128] (init? = : +=) A(bf16)[M][128] @ Bp(packed)
__global__ void k_mfma_acc(const bf16* __restrict__ A, const bf16* __restrict__ Bp,
                           float* __restrict__ C, int M, int init){
  int wave = (blockIdx.x*blockDim.x + threadIdx.x) >> 6;
  int lane = threadIdx.x & 63;
  int rowBase = wave << 4;
  if (rowBase >= M) return;
  long long aRow = rowBase + (lane & 15);
  int kGrp = (lane >> 4) << 3;
  int colB = lane & 15;
  int rowQ = rowBase + ((lane >> 4) << 2);
  floatx4 acc[8];
  if (init){
#pragma unroll
    for (int nt = 0; nt < 8; nt++) acc[nt] = (floatx4){0.f,0.f,0.f,0.f};
  } else {
#pragma unroll
    for (int nt = 0; nt < 8; nt++)
#pragma unroll
      for (int v = 0; v < 4; v++)
        acc[nt][v] = C[(long long)(rowQ+v)*HID + nt*16 + colB];
  }
  const bf16* bp = Bp + lane*8;
#pragma unroll
  for (int kt = 0; kt < 4; kt++){
    short8 a = *(const short8*)(A + aRow*HID + kt*32 + kGrp);
#pragma unroll
    for (int nt = 0; nt < 8; nt++){
      short8 b = *(const short8*)(bp + (nt*4 + kt)*512);
      acc[nt] = __builtin_amdgcn_mfma_f32_16x16x32_bf16(a, b, acc[nt], 0, 0, 0);
    }
  }
#pragma unroll
  for (int nt = 0; nt < 8; nt++)
#pragma unroll
    for (int v = 0; v < 4; v++)
      C[(long long)(rowQ+v)*HID + nt*16 + colB] = acc[nt][v];
}

// MFMA GEMM + relu epilogue: out(bf16)[M][128] = relu(A @ Bp + bias)
__global__ void k_mfma_out(const bf16* __restrict__ A, const bf16* __restrict__ Bp,
                           const float* __restrict__ bias, bf16* __restrict__ out, int M){
  int wave = (blockIdx.x*blockDim.x + threadIdx.x) >> 6;
  int lane = threadIdx.x & 63;
  int rowBase = wave << 4;
  if (rowBase >= M) return;
  long long aRow = rowBase + (lane & 15);
  int kGrp = (lane >> 4) << 3;
  floatx4 acc[8];
#pragma unroll
  for (int nt = 0; nt < 8; nt++) acc[nt] = (floatx4){0.f,0.f,0.f,0.f};
  const bf16* bp = Bp + lane*8;
#pragma unroll
  for (int kt = 0; kt < 4; kt++){
    short8 a = *(const short8*)(A + aRow*HID + kt*32 + kGrp);
#pragma unroll
    for (int nt = 0; nt < 8; nt++){
      short8 b = *(const short8*)(bp + (nt*4 + kt)*512);
      acc[nt] = __builtin_amdgcn_mfma_f32_16x16x32_bf16(a, b, acc[nt], 0, 0, 0);
    }
  }
  int colB = lane & 15;
  int rowQ = rowBase + ((lane >> 4) << 2);
#pragma unroll
  for (int nt = 0; nt < 8; nt++){
    int col = nt*16 + colB;
    float bb = bias[col];
#pragma unroll
    for (int v = 0; v < 4; v++)
      out[(long long)(rowQ+v)*HID + col] = f2b(fmaxf(acc[nt][v] + bb, 0.f));
  }
}

// h(bf16) = maybe-relu(hacc + bias)
__global__ void k_finish(const float* __restrict__ hacc, const float* bias,
                         bf16* __restrict__ h, int relu){
  long long i = (long long)blockIdx.x*256 + threadIdx.x;
  if (i >= (long long)NN*HID) return;
  float x = hacc[i] + bias[(int)(i & 127)];
  if (relu) x = fmaxf(x, 0.f);
  h[i] = f2b(x);
}

// ragged gather + masked mean; flags-dispatched mask (int32 at runtime) + index width
__global__ void k_mean(const bf16* __restrict__ h, const void* ridx, const void* rmask,
                       const int* flags, bf16* __restrict__ mean){
  int row = blockIdx.x;
  int f = threadIdx.x;
  int mt = flags[1];
  int wide = flags[4];
  const int* m4            = (const int*)rmask;
  const unsigned char* m1  = (const unsigned char*)rmask;
  const unsigned short* m2 = (const unsigned short*)rmask;
  const unsigned int* mw   = (const unsigned int*)rmask;
  float acc = 0.f, cnt = 0.f;
  for (int j = 0; j < FF; j++){
    int i = row*FF + j;
    int on;
    if      (mt == 1) on = (m1[i] != 0);
    else if (mt == 2) on = (m2[i] != 0);
    else if (mt == 3) on = (mw[i] != 0);
    else              on = (m4[i] != 0);
    if (on){
      int idx = geti(ridx, i, wide);
      acc += b2f(h[(long long)idx*HID + f]);
      cnt += 1.f;
    }
  }
  mean[(long long)row*HID + f] = f2b(acc / fmaxf(cnt, 1.f));
}

// final layer: out(f32)[NROWS][10]
__global__ void k_last(const bf16* __restrict__ A, const float* __restrict__ B,
                       const float* bias, float* __restrict__ out){
  int i = blockIdx.x*256 + threadIdx.x;
  if (i >= NROWS*NCLS) return;
  int row = i / NCLS, col = i - row*NCLS;
  float acc = bias[col];
  const bf16* ar = A + (long long)row*HID;
  for (int k = 0; k < HID; k++) acc += b2f(ar[k]) * B[k*NCLS + col];
  out[i] = acc;
}

extern "C" void kernel_launch(void* const* d_in, const int* in_sizes, int n_in,
                              void* d_out, int out_size, void* d_ws, size_t ws_size,
                              hipStream_t stream){
  float* out = (float*)d_out;

  static const int expect[17] = {
    NN*64, RR*EE, RR*EE, NROWS*FF, NROWS*FF,
    64*HID, HID, RR*HID*HID, RR*HID, RR*HID*HID, RR*HID,
    HID*HID, HID, HID*HID, HID, HID*NCLS, NCLS };
  bool ok = (n_in >= 17) && (out_size == NROWS*NCLS);
  if (ok) for (int i = 0; i < 17; i++) if (in_sizes[i] != expect[i]) { ok = false; break; }
  if (!ok){
    k_fill<<<(NROWS*NCLS+255)/256, 256, 0, stream>>>(out, NROWS*NCLS, 64.0f);
    return;
  }

  const void*  e_src = d_in[1];
  const void*  e_dst = d_in[2];
  const void*  ridx  = d_in[3];
  const void*  rmask = d_in[4];
  const float* nf   = (const float*)d_in[0];
  const float* W_in = (const float*)d_in[5];
  const float* b_in = (const float*)d_in[6];
  const float* W1   = (const float*)d_in[7];
  const float* b1   = (const float*)d_in[8];
  const float* W2   = (const float*)d_in[9];
  const float* b2   = (const float*)d_in[10];
  const float* Wm1  = (const float*)d_in[11];
  const float* bm1  = (const float*)d_in[12];
  const float* Wm2  = (const float*)d_in[13];
  const float* bm2  = (const float*)d_in[14];
  const float* Wm3  = (const float*)d_in[15];
  const float* bm3  = (const float*)d_in[16];

  char* ws = (char*)d_ws;
  size_t off = 0;
  auto take = [&](size_t bytes)->char*{
    char* p = ws + off; off += (bytes + 255) & ~(size_t)255; return p; };

  int*   flags = (int*)  take(256);
  char*  rgnB  =         take(30720000);            // 30.72 MB multi-use
  float* hacc  = (float*)(rgnB);                    // graph phase: 19.456 MB f32
  bf16*  aggr  = (bf16*) (rgnB + 19456000);         // graph phase: 9.728 MB bf16
  bf16*  meanb = (bf16*) (rgnB);                    // MLP: mean 15.36 MB
  bf16*  x1    = (bf16*) (rgnB + 15360000);         // MLP: x1 15.36 MB
  bf16*  x2    = (bf16*) (rgnB);                    // MLP: x2 overlays dead mean
  bf16*  h1    = (bf16*) take((size_t)NN*HID*2);
  bf16*  h2    = (bf16*) take((size_t)NN*HID*2);
  int*   head  = (int*)  take((size_t)RR*NN*4);
  int*   nxt   = (int*)  take((size_t)RR*EE*4);
  float* ns    = (float*)take((size_t)RR*NN*4);
  float* nd    = (float*)take((size_t)RR*NN*4);
  float* bias  = (float*)take(656*4);
  bf16*  W1p   = (bf16*) take((size_t)RR*16384*2);
  bf16*  W2p   = (bf16*) take((size_t)RR*16384*2);
  bf16*  Wm1p  = (bf16*) take((size_t)16384*2);
  bf16*  Wm2p  = (bf16*) take((size_t)16384*2);

  if (off > ws_size){
    k_fill<<<(NROWS*NCLS+255)/256, 256, 0, stream>>>(out, NROWS*NCLS, 32.0f);
    return;
  }

  k_sniff<<<1, 64, 0, stream>>>(rmask, ridx, e_src, flags);
  k_init <<<(RR*NN+255)/256, 256, 0, stream>>>(head, ns, nd);
  k_graph<<<(RR*EE+255)/256, 256, 0, stream>>>(e_src, e_dst, ns, nd, head, nxt, flags);
  k_norm <<<(RR*NN+255)/256, 256, 0, stream>>>(ns, nd);
  k_bias <<<1, 128, 0, stream>>>(b_in, b1, b2, bm1, bm2, bm3, bias);

  k_pack<<<(RR*16384+255)/256, 256, 0, stream>>>(W1,  W1p,  RR*16384);
  k_pack<<<(RR*16384+255)/256, 256, 0, stream>>>(W2,  W2p,  RR*16384);
  k_pack<<<(16384+255)/256,    256, 0, stream>>>(Wm1, Wm1p, 16384);
  k_pack<<<(16384+255)/256,    256, 0, stream>>>(Wm2, Wm2p, 16384);

  // input linear + relu -> h1 (bf16)
  k_gemm_in<<<NN/4, 128, 0, stream>>>(nf, W_in, bias+0, h1);

  int gN = (NN/16 + 3)/4;      // 594
  int gR = (NROWS/16 + 3)/4;   // 938

  // RGCN layer 1 (relu)
  for (int r = 0; r < RR; r++){
    k_agg_r   <<<NN, 128, 0, stream>>>(h1, e_src, head + r*NN, nxt,
                                       ns + r*NN, nd + r*NN, aggr, flags);
    k_mfma_acc<<<gN, 256, 0, stream>>>(aggr, W1p + r*16384, hacc, NN, r == 0);
  }
  k_finish<<<(NN*HID+255)/256, 256, 0, stream>>>(hacc, bias+128, h2, 1);

  // RGCN layer 2 (no relu)
  for (int r = 0; r < RR; r++){
    k_agg_r   <<<NN, 128, 0, stream>>>(h2, e_src, head + r*NN, nxt,
                                       ns + r*NN, nd + r*NN, aggr, flags);
    k_mfma_acc<<<gN, 256, 0, stream>>>(aggr, W2p + r*16384, hacc, NN, r == 0);
  }
  k_finish<<<(NN*HID+255)/256, 256, 0, stream>>>(hacc, bias+256, h1, 0);

  // masked mean (graph-phase rgnB dead; meanb overlays it)
  k_mean<<<NROWS, 128, 0, stream>>>(h1, ridx, rmask, flags, meanb);

  // MLP head
  k_mfma_out<<<gR, 256, 0, stream>>>(meanb, Wm1p, bias+384, x1, NROWS);
  k_mfma_out<<<gR, 256, 0, stream>>>(x1,    Wm2p, bias+512, x2, NROWS);
  k_last<<<(NROWS*NCLS+255)/256, 256, 0, stream>>>(x2, Wm3, bias+640, out);
}

// Round 14
// 1193.767 us; speedup vs baseline: 2.3749x; 1.1768x over previous
//
#include <hip/hip_runtime.h>
#include <hip/hip_bf16.h>

#define NN    38000
#define HID   128
#define RR    8
#define EE    200000
#define NROWS 60000
#define FF    19
#define NCLS  10

typedef __hip_bfloat16 bf16;
typedef __attribute__((ext_vector_type(8))) short short8;
typedef __attribute__((ext_vector_type(4))) float floatx4;

__device__ __forceinline__ float b2f(bf16 x){ return __bfloat162float(x); }
__device__ __forceinline__ bf16  f2b(float x){ return __float2bfloat16(x); }

__device__ __forceinline__ int geti(const void* a, long long i, int wide){
  return wide ? (int)(((const long long*)a)[i]) : ((const int*)a)[i];
}

__global__ void k_fill(float* out, int n, float v){
  int i = blockIdx.x*256 + threadIdx.x;
  if (i < n) out[i] = v;
}

// r12's proven parallel sniff (1 wave)
__global__ void k_sniff(const void* mask, const void* ridx, const void* esrc, int* flags){
  int lane = threadIdx.x;    // blockDim = 64
  const unsigned short* mu = (const unsigned short*)mask;
  int l3f80e=0, l3f80o=0, lbytehi=0, loddnz=0, lother=0;
  for (int i = lane; i < 4096; i += 64){
    unsigned v = mu[i];
    if (v == 0) continue;
    if (v == 0x3F80){ if (i & 1) l3f80o = 1; else l3f80e = 1; continue; }
    unsigned lo = v & 0xFF, hi = v >> 8;
    int lob = (lo == 0 || lo == 1 || lo == 0xFF);
    int hib = (hi == 0 || hi == 1 || hi == 0xFF);
    if (lob && hib){ if (hi) lbytehi = 1; if (i & 1) loddnz = 1; continue; }
    lother = 1;
  }
  int a3f80e = __any(l3f80e);
  int a3f80o = __any(l3f80o);
  int abytehi = __any(lbytehi);
  int aoddnz = __any(loddnz);
  int aother = __any(lother);
  int mtype = -1;
  if (!aother){
    if (a3f80e && !abytehi && !aoddnz)       mtype = 2;
    else if (a3f80o && !a3f80e && !abytehi)  mtype = 3;
    else if (!a3f80e && !a3f80o){
      if (abytehi || aoddnz) mtype = 1;
      else                   mtype = 0;     // int32 0/1 (actual runtime case)
    }
  }
  const int* es = (const int*)esrc;
  int loddE = 0, lseenE = 0;
  for (int i = lane; i < 512; i += 64){
    if (es[2*i+1] != 0) loddE = 1;
    if (es[2*i] > 1)    lseenE = 1;
  }
  int fE = (!__any(loddE) && __any(lseenE)) ? 1 : 0;
  const int* ri = (const int*)ridx;
  int loddI = 0, lseenI = 0;
  for (int i = lane; i < 512; i += 64){
    if (ri[2*i+1] != 0) loddI = 1;
    if (ri[2*i] > 1)    lseenI = 1;
  }
  int fI = (!__any(loddI) && __any(lseenI)) ? 1 : 0;
  if (lane == 0){ flags[1] = mtype; flags[3] = fE; flags[4] = fI; }
}

__global__ void k_init(int* head, float* cs){
  int i = blockIdx.x*256 + threadIdx.x;
  if (i >= RR*NN) return;
  head[i] = -1; cs[i] = 0.f;
}

// 2 atomics/edge (dst in-degree now counted during the agg walk)
__global__ void k_graph(const void* src, const void* dst,
                        float* cs, int* head, int* nxt, const int* flags){
  int i = blockIdx.x*256 + threadIdx.x;
  if (i >= RR*EE) return;
  int wide = flags[3];
  int r = i / EE;
  int s = geti(src, i, wide);
  int d = geti(dst, i, wide);
  atomicAdd(cs + r*NN + s, 1.0f);
  nxt[i] = atomicExch(head + r*NN + d, i);
}

__global__ void k_norm(float* cs){
  int i = blockIdx.x*256 + threadIdx.x;
  if (i >= RR*NN) return;
  float a = cs[i]; cs[i] = rsqrtf(a > 0.f ? a : 1.f);
}

__global__ void k_bias(const float* b_in, const float* b1, const float* b2,
                       const float* bm1, const float* bm2, const float* bm3, float* o){
  int t = threadIdx.x;
  o[t] = b_in[t];
  float s1 = 0.f, s2 = 0.f;
  for (int r = 0; r < RR; r++){ s1 += b1[r*HID+t]; s2 += b2[r*HID+t]; }
  o[128+t] = s1; o[256+t] = s2;
  o[384+t] = bm1[t]; o[512+t] = bm2[t];
  if (t < NCLS) o[640+t] = bm3[t];
}

// pack [8][128][128] f32 weights into K=512 MFMA B-frag order, 2 groups of 4 rel
// out idx = g*65536 + (nt*16+ktg)*512 + l*8 + j
__global__ void k_pack512(const float* __restrict__ W, bf16* __restrict__ out){
  int idx = blockIdx.x*256 + threadIdx.x;
  if (idx >= 2*65536) return;
  int j = idx & 7;
  int l = (idx >> 3) & 63;
  int t = (idx >> 9) & 127;   // nt*16 + ktg
  int g = idx >> 16;
  int ktg = t & 15, nt = t >> 4;
  int kglob = ktg*32 + ((l>>4)<<3) + j;
  int rel = kglob >> 7;
  int krow = kglob & 127;
  int n = nt*16 + (l&15);
  out[idx] = f2b(W[((g*4 + rel)*128 + krow)*128 + n]);
}

// K=128 pack for MLP weights (r13-proven layout)
__global__ void k_pack(const float* __restrict__ B, bf16* __restrict__ out, int total){
  int idx = blockIdx.x*256 + threadIdx.x;
  if (idx >= total) return;
  int j  = idx & 7;
  int l  = (idx >> 3) & 63;
  int t  = (idx >> 9) & 31;
  int kt = t & 3;
  int nt = t >> 2;
  int k = kt*32 + ((l>>4)<<3) + j;
  int n = nt*16 + (l&15);
  out[idx] = f2b(B[k*128 + n]);
}

// input linear + relu (f32 VALU, K=64) -> h1 bf16
__global__ void k_gemm_in(const float* __restrict__ A, const float* __restrict__ B,
                          const float* bias, bf16* __restrict__ out){
  int row0 = blockIdx.x * 4;
  int col = threadIdx.x;
  float a0=0.f, a1=0.f, a2=0.f, a3=0.f;
  for (int k = 0; k < 64; k++){
    float bv = B[k*HID + col];
    a0 += A[(long long)(row0+0)*64 + k] * bv;
    a1 += A[(long long)(row0+1)*64 + k] * bv;
    a2 += A[(long long)(row0+2)*64 + k] * bv;
    a3 += A[(long long)(row0+3)*64 + k] * bv;
  }
  float bb = bias[col];
  out[(long long)(row0+0)*HID + col] = f2b(fmaxf(a0 + bb, 0.f));
  out[(long long)(row0+1)*HID + col] = f2b(fmaxf(a1 + bb, 0.f));
  out[(long long)(row0+2)*HID + col] = f2b(fmaxf(a2 + bb, 0.f));
  out[(long long)(row0+3)*HID + col] = f2b(fmaxf(a3 + bb, 0.f));
}

// 4 relations' aggregation in one launch; dst degree counted in-walk
__global__ void k_agg4(const bf16* __restrict__ h, const void* src,
                       const int* __restrict__ head, const int* __restrict__ nxt,
                       const float* __restrict__ ns, bf16* __restrict__ slab,
                       int rbase, const int* flags){
  int b = blockIdx.x;          // 0 .. 4*NN
  int rloc = b / NN;
  int d = b - rloc*NN;
  int r = rbase + rloc;
  int f = threadIdx.x;
  int wide = flags[3];
  float acc = 0.f, cnt = 0.f;
  int e = head[r*NN + d];
  while (e >= 0){
    int s  = geti(src, e, wide);
    int en = nxt[e];
    acc += ns[r*NN + s] * b2f(h[(long long)s*HID + f]);
    cnt += 1.f;
    e = en;
  }
  slab[((long long)rloc*NN + d)*HID + f] = f2b(acc * rsqrtf(cnt > 0.f ? cnt : 1.f));
}

// K=512 MFMA over the [4][NN][128] slab.
// mode 0: Cout(f32) = slab @ Bp ; mode 1: hout(bf16) = act(Cin + slab @ Bp + bias)
__global__ void k_mfma512(const bf16* __restrict__ slab, const bf16* __restrict__ Bp,
                          const float* __restrict__ Cin, const float* __restrict__ bias,
                          float* __restrict__ Cout, bf16* __restrict__ hout,
                          int mode, int relu){
  int wave = (blockIdx.x*blockDim.x + threadIdx.x) >> 6;
  int lane = threadIdx.x & 63;
  int rowBase = wave << 4;
  if (rowBase >= NN) return;
  long long aRow = rowBase + (lane & 15);
  int kGrp = (lane >> 4) << 3;
  floatx4 acc[8];
#pragma unroll
  for (int nt = 0; nt < 8; nt++) acc[nt] = (floatx4){0.f,0.f,0.f,0.f};
  const bf16* bp = Bp + lane*8;
#pragma unroll
  for (int kt = 0; kt < 16; kt++){
    int rel = kt >> 2;
    short8 a = *(const short8*)(slab + ((long long)rel*NN + aRow)*HID + (kt&3)*32 + kGrp);
#pragma unroll
    for (int nt = 0; nt < 8; nt++){
      short8 b = *(const short8*)(bp + (nt*16 + kt)*512);
      acc[nt] = __builtin_amdgcn_mfma_f32_16x16x32_bf16(a, b, acc[nt], 0, 0, 0);
    }
  }
  int colB = lane & 15;
  int rowQ = rowBase + ((lane >> 4) << 2);
  if (mode == 0){
#pragma unroll
    for (int nt = 0; nt < 8; nt++)
#pragma unroll
      for (int v = 0; v < 4; v++)
        Cout[(long long)(rowQ+v)*HID + nt*16 + colB] = acc[nt][v];
  } else {
#pragma unroll
    for (int nt = 0; nt < 8; nt++){
      int col = nt*16 + colB;
      float bb = bias[col];
#pragma unroll
      for (int v = 0; v < 4; v++){
        float x = acc[nt][v] + Cin[(long long)(rowQ+v)*HID + col] + bb;
        if (relu) x = fmaxf(x, 0.f);
        hout[(long long)(rowQ+v)*HID + col] = f2b(x);
      }
    }
  }
}

// MLP K=128 MFMA + relu epilogue (r13-proven)
__global__ void k_mfma_out(const bf16* __restrict__ A, const bf16* __restrict__ Bp,
                           const float* __restrict__ bias, bf16* __restrict__ out, int M){
  int wave = (blockIdx.x*blockDim.x + threadIdx.x) >> 6;
  int lane = threadIdx.x & 63;
  int rowBase = wave << 4;
  if (rowBase >= M) return;
  long long aRow = rowBase + (lane & 15);
  int kGrp = (lane >> 4) << 3;
  floatx4 acc[8];
#pragma unroll
  for (int nt = 0; nt < 8; nt++) acc[nt] = (floatx4){0.f,0.f,0.f,0.f};
  const bf16* bp = Bp + lane*8;
#pragma unroll
  for (int kt = 0; kt < 4; kt++){
    short8 a = *(const short8*)(A + aRow*HID + kt*32 + kGrp);
#pragma unroll
    for (int nt = 0; nt < 8; nt++){
      short8 b = *(const short8*)(bp + (nt*4 + kt)*512);
      acc[nt] = __builtin_amdgcn_mfma_f32_16x16x32_bf16(a, b, acc[nt], 0, 0, 0);
    }
  }
  int colB = lane & 15;
  int rowQ = rowBase + ((lane >> 4) << 2);
#pragma unroll
  for (int nt = 0; nt < 8; nt++){
    int col = nt*16 + colB;
    float bb = bias[col];
#pragma unroll
    for (int v = 0; v < 4; v++)
      out[(long long)(rowQ+v)*HID + col] = f2b(fmaxf(acc[nt][v] + bb, 0.f));
  }
}

// ragged gather + masked mean; flags-dispatched mask + index width (proven)
__global__ void k_mean(const bf16* __restrict__ h, const void* ridx, const void* rmask,
                       const int* flags, bf16* __restrict__ mean){
  int row = blockIdx.x;
  int f = threadIdx.x;
  int mt = flags[1];
  int wide = flags[4];
  const int* m4            = (const int*)rmask;
  const unsigned char* m1  = (const unsigned char*)rmask;
  const unsigned short* m2 = (const unsigned short*)rmask;
  const unsigned int* mw   = (const unsigned int*)rmask;
  float acc = 0.f, cnt = 0.f;
  for (int j = 0; j < FF; j++){
    int i = row*FF + j;
    int on;
    if      (mt == 1) on = (m1[i] != 0);
    else if (mt == 2) on = (m2[i] != 0);
    else if (mt == 3) on = (mw[i] != 0);
    else              on = (m4[i] != 0);
    if (on){
      int idx = geti(ridx, i, wide);
      acc += b2f(h[(long long)idx*HID + f]);
      cnt += 1.f;
    }
  }
  mean[(long long)row*HID + f] = f2b(acc / fmaxf(cnt, 1.f));
}

// final layer: out(f32)[NROWS][10]
__global__ void k_last(const bf16* __restrict__ A, const float* __restrict__ B,
                       const float* bias, float* __restrict__ out){
  int i = blockIdx.x*256 + threadIdx.x;
  if (i >= NROWS*NCLS) return;
  int row = i / NCLS, col = i - row*NCLS;
  float acc = bias[col];
  const bf16* ar = A + (long long)row*HID;
  for (int k = 0; k < HID; k++) acc += b2f(ar[k]) * B[k*NCLS + col];
  out[i] = acc;
}

extern "C" void kernel_launch(void* const* d_in, const int* in_sizes, int n_in,
                              void* d_out, int out_size, void* d_ws, size_t ws_size,
                              hipStream_t stream){
  float* out = (float*)d_out;

  static const int expect[17] = {
    NN*64, RR*EE, RR*EE, NROWS*FF, NROWS*FF,
    64*HID, HID, RR*HID*HID, RR*HID, RR*HID*HID, RR*HID,
    HID*HID, HID, HID*HID, HID, HID*NCLS, NCLS };
  bool ok = (n_in >= 17) && (out_size == NROWS*NCLS);
  if (ok) for (int i = 0; i < 17; i++) if (in_sizes[i] != expect[i]) { ok = false; break; }
  if (!ok){
    k_fill<<<(NROWS*NCLS+255)/256, 256, 0, stream>>>(out, NROWS*NCLS, 64.0f);
    return;
  }

  const void*  e_src = d_in[1];
  const void*  e_dst = d_in[2];
  const void*  ridx  = d_in[3];
  const void*  rmask = d_in[4];
  const float* nf   = (const float*)d_in[0];
  const float* W_in = (const float*)d_in[5];
  const float* b_in = (const float*)d_in[6];
  const float* W1   = (const float*)d_in[7];
  const float* b1   = (const float*)d_in[8];
  const float* W2   = (const float*)d_in[9];
  const float* b2   = (const float*)d_in[10];
  const float* Wm1  = (const float*)d_in[11];
  const float* bm1  = (const float*)d_in[12];
  const float* Wm2  = (const float*)d_in[13];
  const float* bm2  = (const float*)d_in[14];
  const float* Wm3  = (const float*)d_in[15];
  const float* bm3  = (const float*)d_in[16];

  char* ws = (char*)d_ws;
  size_t off = 0;
  auto take = [&](size_t bytes)->char*{
    char* p = ws + off; off += (bytes + 255) & ~(size_t)255; return p; };

  int*   flags = (int*)  take(256);
  char*  rgn   =         take(58368000);            // 58.37 MB multi-use
  bf16*  slab  = (bf16*) (rgn);                     // graph: [4][NN][128] 38.912 MB
  float* hacc  = (float*)(rgn + 38912000);          // graph: 19.456 MB f32
  bf16*  meanb = (bf16*) (rgn);                     // MLP: 15.36 MB
  bf16*  x1    = (bf16*) (rgn + 15360000);          // MLP: 15.36 MB
  bf16*  x2    = (bf16*) (rgn + 30720000);          // MLP: 15.36 MB
  bf16*  h1    = (bf16*) take((size_t)NN*HID*2);
  bf16*  h2    = (bf16*) take((size_t)NN*HID*2);
  int*   head  = (int*)  take((size_t)RR*NN*4);
  int*   nxt   = (int*)  take((size_t)RR*EE*4);
  float* ns    = (float*)take((size_t)RR*NN*4);
  float* bias  = (float*)take(656*4);
  bf16*  W1p   = (bf16*) take((size_t)2*65536*2);
  bf16*  W2p   = (bf16*) take((size_t)2*65536*2);
  bf16*  Wm1p  = (bf16*) take((size_t)16384*2);
  bf16*  Wm2p  = (bf16*) take((size_t)16384*2);

  if (off > ws_size){
    k_fill<<<(NROWS*NCLS+255)/256, 256, 0, stream>>>(out, NROWS*NCLS, 32.0f);
    return;
  }

  k_sniff<<<1, 64, 0, stream>>>(rmask, ridx, e_src, flags);
  k_init <<<(RR*NN+255)/256, 256, 0, stream>>>(head, ns);
  k_graph<<<(RR*EE+255)/256, 256, 0, stream>>>(e_src, e_dst, ns, head, nxt, flags);
  k_norm <<<(RR*NN+255)/256, 256, 0, stream>>>(ns);
  k_bias <<<1, 128, 0, stream>>>(b_in, b1, b2, bm1, bm2, bm3, bias);

  k_pack512<<<(2*65536+255)/256, 256, 0, stream>>>(W1, W1p);
  k_pack512<<<(2*65536+255)/256, 256, 0, stream>>>(W2, W2p);
  k_pack<<<(16384+255)/256, 256, 0, stream>>>(Wm1, Wm1p, 16384);
  k_pack<<<(16384+255)/256, 256, 0, stream>>>(Wm2, Wm2p, 16384);

  // input linear + relu -> h1 (bf16)
  k_gemm_in<<<NN/4, 128, 0, stream>>>(nf, W_in, bias+0, h1);

  int gN = (NN/16 + 3)/4;      // 594 blocks (4 waves each)
  int gR = (NROWS/16 + 3)/4;   // 938

  // RGCN layer 1 (relu): relations 0-3 then 4-7
  k_agg4   <<<4*NN, 128, 0, stream>>>(h1, e_src, head, nxt, ns, slab, 0, flags);
  k_mfma512<<<gN, 256, 0, stream>>>(slab, W1p,          nullptr, nullptr, hacc, nullptr, 0, 0);
  k_agg4   <<<4*NN, 128, 0, stream>>>(h1, e_src, head, nxt, ns, slab, 4, flags);
  k_mfma512<<<gN, 256, 0, stream>>>(slab, W1p + 65536,  hacc, bias+128, nullptr, h2, 1, 1);

  // RGCN layer 2 (no relu)
  k_agg4   <<<4*NN, 128, 0, stream>>>(h2, e_src, head, nxt, ns, slab, 0, flags);
  k_mfma512<<<gN, 256, 0, stream>>>(slab, W2p,          nullptr, nullptr, hacc, nullptr, 0, 0);
  k_agg4   <<<4*NN, 128, 0, stream>>>(h2, e_src, head, nxt, ns, slab, 4, flags);
  k_mfma512<<<gN, 256, 0, stream>>>(slab, W2p + 65536,  hacc, bias+256, nullptr, h1, 1, 0);

  // masked mean (graph-phase rgn dead; meanb overlays it)
  k_mean<<<NROWS, 128, 0, stream>>>(h1, ridx, rmask, flags, meanb);

  // MLP head
  k_mfma_out<<<gR, 256, 0, stream>>>(meanb, Wm1p, bias+384, x1, NROWS);
  k_mfma_out<<<gR, 256, 0, stream>>>(x1,    Wm2p, bias+512, x2, NROWS);
  k_last<<<(NROWS*NCLS+255)/256, 256, 0, stream>>>(x2, Wm3, bias+640, out);
}

// Round 15
// 1135.136 us; speedup vs baseline: 2.4975x; 1.0517x over previous
//
#include <hip/hip_runtime.h>
#include <hip/hip_bf16.h>

#define NN    38000
#define HID   128
#define RR    8
#define EE    200000
#define NROWS 60000
#define FF    19
#define NCLS  10
#define NRD   (RR*NN)         // 304000
#define NBLK  ((NRD+255)/256) // 1188

typedef __hip_bfloat16 bf16;
typedef __attribute__((ext_vector_type(8))) short short8;
typedef __attribute__((ext_vector_type(4))) float floatx4;

__device__ __forceinline__ float b2f(bf16 x){ return __bfloat162float(x); }
__device__ __forceinline__ bf16  f2b(float x){ return __float2bfloat16(x); }

__device__ __forceinline__ int geti(const void* a, long long i, int wide){
  return wide ? (int)(((const long long*)a)[i]) : ((const int*)a)[i];
}

__global__ void k_fill(float* out, int n, float v){
  int i = blockIdx.x*256 + threadIdx.x;
  if (i < n) out[i] = v;
}

// r12's proven parallel sniff (1 wave)
__global__ void k_sniff(const void* mask, const void* ridx, const void* esrc, int* flags){
  int lane = threadIdx.x;    // blockDim = 64
  const unsigned short* mu = (const unsigned short*)mask;
  int l3f80e=0, l3f80o=0, lbytehi=0, loddnz=0, lother=0;
  for (int i = lane; i < 4096; i += 64){
    unsigned v = mu[i];
    if (v == 0) continue;
    if (v == 0x3F80){ if (i & 1) l3f80o = 1; else l3f80e = 1; continue; }
    unsigned lo = v & 0xFF, hi = v >> 8;
    int lob = (lo == 0 || lo == 1 || lo == 0xFF);
    int hib = (hi == 0 || hi == 1 || hi == 0xFF);
    if (lob && hib){ if (hi) lbytehi = 1; if (i & 1) loddnz = 1; continue; }
    lother = 1;
  }
  int a3f80e = __any(l3f80e);
  int a3f80o = __any(l3f80o);
  int abytehi = __any(lbytehi);
  int aoddnz = __any(loddnz);
  int aother = __any(lother);
  int mtype = -1;
  if (!aother){
    if (a3f80e && !abytehi && !aoddnz)       mtype = 2;
    else if (a3f80o && !a3f80e && !abytehi)  mtype = 3;
    else if (!a3f80e && !a3f80o){
      if (abytehi || aoddnz) mtype = 1;
      else                   mtype = 0;     // int32 0/1 (actual runtime case)
    }
  }
  const int* es = (const int*)esrc;
  int loddE = 0, lseenE = 0;
  for (int i = lane; i < 512; i += 64){
    if (es[2*i+1] != 0) loddE = 1;
    if (es[2*i] > 1)    lseenE = 1;
  }
  int fE = (!__any(loddE) && __any(lseenE)) ? 1 : 0;
  const int* ri = (const int*)ridx;
  int loddI = 0, lseenI = 0;
  for (int i = lane; i < 512; i += 64){
    if (ri[2*i+1] != 0) loddI = 1;
    if (ri[2*i] > 1)    lseenI = 1;
  }
  int fI = (!__any(loddI) && __any(lseenI)) ? 1 : 0;
  if (lane == 0){ flags[1] = mtype; flags[3] = fE; flags[4] = fI; }
}

__global__ void k_init0(float* cs, int* degI){
  int i = blockIdx.x*256 + threadIdx.x;
  if (i >= NRD) return;
  cs[i] = 0.f; degI[i] = 0;
}

// degree pass: 2 atomics/edge (src out-degree f32, dst in-degree int)
__global__ void k_deg(const void* src, const void* dst,
                      float* cs, int* degI, const int* flags){
  int i = blockIdx.x*256 + threadIdx.x;
  if (i >= RR*EE) return;
  int wide = flags[3];
  int r = i / EE;
  int s = geti(src, i, wide);
  int d = geti(dst, i, wide);
  atomicAdd(cs + r*NN + s, 1.0f);
  atomicAdd(degI + r*NN + d, 1);
}

// block-local exclusive scan of degI -> rowptr; block totals -> blksum
__global__ void k_scan1(const int* degI, int* rowptr, int* blksum){
  __shared__ int ls[256];
  int t = threadIdx.x;
  int i = blockIdx.x*256 + t;
  int v = (i < NRD) ? degI[i] : 0;
  ls[t] = v;
  __syncthreads();
  for (int off = 1; off < 256; off <<= 1){
    int tv = (t >= off) ? ls[t-off] : 0;
    __syncthreads();
    ls[t] += tv;
    __syncthreads();
  }
  if (i < NRD) rowptr[i] = ls[t] - v;       // exclusive within block
  if (t == 255) blksum[blockIdx.x] = ls[255];
}

// scan of 1188 block totals -> exclusive block offsets (single block)
__global__ void k_scan2(int* blksum){
  __shared__ int ls[2048];
  int t = threadIdx.x;   // 256
  for (int i = t; i < 2048; i += 256) ls[i] = (i < NBLK) ? blksum[i] : 0;
  __syncthreads();
  for (int off = 1; off < 2048; off <<= 1){
    int tmp[8];
#pragma unroll
    for (int j = 0; j < 8; j++){ int idx = t + j*256; tmp[j] = (idx >= off) ? ls[idx-off] : 0; }
    __syncthreads();
#pragma unroll
    for (int j = 0; j < 8; j++){ int idx = t + j*256; ls[idx] += tmp[j]; }
    __syncthreads();
  }
  for (int i = t; i < NBLK; i += 256) blksum[i] = (i == 0) ? 0 : ls[i-1];
}

// finalize rowptr (+block offset), cursor = rowptr copy
__global__ void k_scan3(int* rowptr, const int* blksum, int* cursor){
  int i = blockIdx.x*256 + threadIdx.x;
  if (i >= NRD) return;
  int v = rowptr[i] + blksum[i >> 8];
  rowptr[i] = v;
  cursor[i] = v;
  if (i == 0) rowptr[NRD] = RR*EE;
}

// scatter edges into CSR: 1 atomic + 1 store per edge
__global__ void k_scatter(const void* src, const void* dst,
                          int* cursor, int* csr, const int* flags){
  int i = blockIdx.x*256 + threadIdx.x;
  if (i >= RR*EE) return;
  int wide = flags[3];
  int r = i / EE;
  int s = geti(src, i, wide);
  int d = geti(dst, i, wide);
  int pos = atomicAdd(cursor + r*NN + d, 1);
  csr[pos] = s;
}

__global__ void k_norm(float* cs){
  int i = blockIdx.x*256 + threadIdx.x;
  if (i >= NRD) return;
  float a = cs[i]; cs[i] = rsqrtf(a > 0.f ? a : 1.f);
}

__global__ void k_bias(const float* b_in, const float* b1, const float* b2,
                       const float* bm1, const float* bm2, const float* bm3, float* o){
  int t = threadIdx.x;
  o[t] = b_in[t];
  float s1 = 0.f, s2 = 0.f;
  for (int r = 0; r < RR; r++){ s1 += b1[r*HID+t]; s2 += b2[r*HID+t]; }
  o[128+t] = s1; o[256+t] = s2;
  o[384+t] = bm1[t]; o[512+t] = bm2[t];
  if (t < NCLS) o[640+t] = bm3[t];
}

// pack BOTH [8][128][128] weight stacks into K=512 MFMA B-frag order (2 groups each)
__global__ void k_pack512(const float* __restrict__ WA, const float* __restrict__ WB,
                          bf16* __restrict__ outA, bf16* __restrict__ outB){
  int idx0 = blockIdx.x*256 + threadIdx.x;
  if (idx0 >= 4*65536) return;
  const float* W = (idx0 < 2*65536) ? WA : WB;
  bf16* out      = (idx0 < 2*65536) ? outA : outB;
  int idx = idx0 & (2*65536 - 1);
  int j = idx & 7;
  int l = (idx >> 3) & 63;
  int t = (idx >> 9) & 127;   // nt*16 + ktg
  int g = idx >> 16;
  int ktg = t & 15, nt = t >> 4;
  int kglob = ktg*32 + ((l>>4)<<3) + j;
  int rel = kglob >> 7;
  int krow = kglob & 127;
  int n = nt*16 + (l&15);
  out[idx] = f2b(W[((g*4 + rel)*128 + krow)*128 + n]);
}

// pack BOTH MLP weights into K=128 frag order
__global__ void k_packm(const float* __restrict__ WA, const float* __restrict__ WB,
                        bf16* __restrict__ outA, bf16* __restrict__ outB){
  int idx0 = blockIdx.x*256 + threadIdx.x;
  if (idx0 >= 2*16384) return;
  const float* B = (idx0 < 16384) ? WA : WB;
  bf16* out      = (idx0 < 16384) ? outA : outB;
  int idx = idx0 & 16383;
  int j  = idx & 7;
  int l  = (idx >> 3) & 63;
  int t  = (idx >> 9) & 31;
  int kt = t & 3;
  int nt = t >> 2;
  int k = kt*32 + ((l>>4)<<3) + j;
  int n = nt*16 + (l&15);
  out[idx] = f2b(B[k*128 + n]);
}

// input linear + relu (f32 VALU, K=64) -> h1 bf16
__global__ void k_gemm_in(const float* __restrict__ A, const float* __restrict__ B,
                          const float* bias, bf16* __restrict__ out){
  int row0 = blockIdx.x * 4;
  int col = threadIdx.x;
  float a0=0.f, a1=0.f, a2=0.f, a3=0.f;
  for (int k = 0; k < 64; k++){
    float bv = B[k*HID + col];
    a0 += A[(long long)(row0+0)*64 + k] * bv;
    a1 += A[(long long)(row0+1)*64 + k] * bv;
    a2 += A[(long long)(row0+2)*64 + k] * bv;
    a3 += A[(long long)(row0+3)*64 + k] * bv;
  }
  float bb = bias[col];
  out[(long long)(row0+0)*HID + col] = f2b(fmaxf(a0 + bb, 0.f));
  out[(long long)(row0+1)*HID + col] = f2b(fmaxf(a1 + bb, 0.f));
  out[(long long)(row0+2)*HID + col] = f2b(fmaxf(a2 + bb, 0.f));
  out[(long long)(row0+3)*HID + col] = f2b(fmaxf(a3 + bb, 0.f));
}

// 4 relations' aggregation via CSR (contiguous edge lists, no pointer chase)
__global__ void k_agg4(const bf16* __restrict__ h, const int* __restrict__ rowptr,
                       const int* __restrict__ csr, const float* __restrict__ ns,
                       bf16* __restrict__ slab, int rbase){
  int b = blockIdx.x;          // 0 .. 4*NN
  int rloc = b / NN;
  int d = b - rloc*NN;
  int r = rbase + rloc;
  int f = threadIdx.x;
  int rd = r*NN + d;
  int beg = rowptr[rd], end = rowptr[rd+1];
  int deg = end - beg;
  float acc = 0.f;
  for (int i = beg; i < end; i++){
    int s = csr[i];
    acc += ns[r*NN + s] * b2f(h[(long long)s*HID + f]);
  }
  float nd = rsqrtf((float)(deg > 0 ? deg : 1));
  slab[((long long)rloc*NN + d)*HID + f] = f2b(acc * nd);
}

// K=512 MFMA over the [4][NN][128] slab (r14-proven)
__global__ void k_mfma512(const bf16* __restrict__ slab, const bf16* __restrict__ Bp,
                          const float* __restrict__ Cin, const float* __restrict__ bias,
                          float* __restrict__ Cout, bf16* __restrict__ hout,
                          int mode, int relu){
  int wave = (blockIdx.x*blockDim.x + threadIdx.x) >> 6;
  int lane = threadIdx.x & 63;
  int rowBase = wave << 4;
  if (rowBase >= NN) return;
  long long aRow = rowBase + (lane & 15);
  int kGrp = (lane >> 4) << 3;
  floatx4 acc[8];
#pragma unroll
  for (int nt = 0; nt < 8; nt++) acc[nt] = (floatx4){0.f,0.f,0.f,0.f};
  const bf16* bp = Bp + lane*8;
#pragma unroll
  for (int kt = 0; kt < 16; kt++){
    int rel = kt >> 2;
    short8 a = *(const short8*)(slab + ((long long)rel*NN + aRow)*HID + (kt&3)*32 + kGrp);
#pragma unroll
    for (int nt = 0; nt < 8; nt++){
      short8 b = *(const short8*)(bp + (nt*16 + kt)*512);
      acc[nt] = __builtin_amdgcn_mfma_f32_16x16x32_bf16(a, b, acc[nt], 0, 0, 0);
    }
  }
  int colB = lane & 15;
  int rowQ = rowBase + ((lane >> 4) << 2);
  if (mode == 0){
#pragma unroll
    for (int nt = 0; nt < 8; nt++)
#pragma unroll
      for (int v = 0; v < 4; v++)
        Cout[(long long)(rowQ+v)*HID + nt*16 + colB] = acc[nt][v];
  } else {
#pragma unroll
    for (int nt = 0; nt < 8; nt++){
      int col = nt*16 + colB;
      float bb = bias[col];
#pragma unroll
      for (int v = 0; v < 4; v++){
        float x = acc[nt][v] + Cin[(long long)(rowQ+v)*HID + col] + bb;
        if (relu) x = fmaxf(x, 0.f);
        hout[(long long)(rowQ+v)*HID + col] = f2b(x);
      }
    }
  }
}

// MLP K=128 MFMA + relu epilogue (r13-proven)
__global__ void k_mfma_out(const bf16* __restrict__ A, const bf16* __restrict__ Bp,
                           const float* __restrict__ bias, bf16* __restrict__ out, int M){
  int wave = (blockIdx.x*blockDim.x + threadIdx.x) >> 6;
  int lane = threadIdx.x & 63;
  int rowBase = wave << 4;
  if (rowBase >= M) return;
  long long aRow = rowBase + (lane & 15);
  int kGrp = (lane >> 4) << 3;
  floatx4 acc[8];
#pragma unroll
  for (int nt = 0; nt < 8; nt++) acc[nt] = (floatx4){0.f,0.f,0.f,0.f};
  const bf16* bp = Bp + lane*8;
#pragma unroll
  for (int kt = 0; kt < 4; kt++){
    short8 a = *(const short8*)(A + aRow*HID + kt*32 + kGrp);
#pragma unroll
    for (int nt = 0; nt < 8; nt++){
      short8 b = *(const short8*)(bp + (nt*4 + kt)*512);
      acc[nt] = __builtin_amdgcn_mfma_f32_16x16x32_bf16(a, b, acc[nt], 0, 0, 0);
    }
  }
  int colB = lane & 15;
  int rowQ = rowBase + ((lane >> 4) << 2);
#pragma unroll
  for (int nt = 0; nt < 8; nt++){
    int col = nt*16 + colB;
    float bb = bias[col];
#pragma unroll
    for (int v = 0; v < 4; v++)
      out[(long long)(rowQ+v)*HID + col] = f2b(fmaxf(acc[nt][v] + bb, 0.f));
  }
}

// ragged gather + masked mean; flags-dispatched mask + index width (proven)
__global__ void k_mean(const bf16* __restrict__ h, const void* ridx, const void* rmask,
                       const int* flags, bf16* __restrict__ mean){
  int row = blockIdx.x;
  int f = threadIdx.x;
  int mt = flags[1];
  int wide = flags[4];
  const int* m4            = (const int*)rmask;
  const unsigned char* m1  = (const unsigned char*)rmask;
  const unsigned short* m2 = (const unsigned short*)rmask;
  const unsigned int* mw   = (const unsigned int*)rmask;
  float acc = 0.f, cnt = 0.f;
  for (int j = 0; j < FF; j++){
    int i = row*FF + j;
    int on;
    if      (mt == 1) on = (m1[i] != 0);
    else if (mt == 2) on = (m2[i] != 0);
    else if (mt == 3) on = (mw[i] != 0);
    else              on = (m4[i] != 0);
    if (on){
      int idx = geti(ridx, i, wide);
      acc += b2f(h[(long long)idx*HID + f]);
      cnt += 1.f;
    }
  }
  mean[(long long)row*HID + f] = f2b(acc / fmaxf(cnt, 1.f));
}

// final layer: out(f32)[NROWS][10]
__global__ void k_last(const bf16* __restrict__ A, const float* __restrict__ B,
                       const float* bias, float* __restrict__ out){
  int i = blockIdx.x*256 + threadIdx.x;
  if (i >= NROWS*NCLS) return;
  int row = i / NCLS, col = i - row*NCLS;
  float acc = bias[col];
  const bf16* ar = A + (long long)row*HID;
  for (int k = 0; k < HID; k++) acc += b2f(ar[k]) * B[k*NCLS + col];
  out[i] = acc;
}

extern "C" void kernel_launch(void* const* d_in, const int* in_sizes, int n_in,
                              void* d_out, int out_size, void* d_ws, size_t ws_size,
                              hipStream_t stream){
  float* out = (float*)d_out;

  static const int expect[17] = {
    NN*64, RR*EE, RR*EE, NROWS*FF, NROWS*FF,
    64*HID, HID, RR*HID*HID, RR*HID, RR*HID*HID, RR*HID,
    HID*HID, HID, HID*HID, HID, HID*NCLS, NCLS };
  bool ok = (n_in >= 17) && (out_size == NROWS*NCLS);
  if (ok) for (int i = 0; i < 17; i++) if (in_sizes[i] != expect[i]) { ok = false; break; }
  if (!ok){
    k_fill<<<(NROWS*NCLS+255)/256, 256, 0, stream>>>(out, NROWS*NCLS, 64.0f);
    return;
  }

  const void*  e_src = d_in[1];
  const void*  e_dst = d_in[2];
  const void*  ridx  = d_in[3];
  const void*  rmask = d_in[4];
  const float* nf   = (const float*)d_in[0];
  const float* W_in = (const float*)d_in[5];
  const float* b_in = (const float*)d_in[6];
  const float* W1   = (const float*)d_in[7];
  const float* b1   = (const float*)d_in[8];
  const float* W2   = (const float*)d_in[9];
  const float* b2   = (const float*)d_in[10];
  const float* Wm1  = (const float*)d_in[11];
  const float* bm1  = (const float*)d_in[12];
  const float* Wm2  = (const float*)d_in[13];
  const float* bm2  = (const float*)d_in[14];
  const float* Wm3  = (const float*)d_in[15];
  const float* bm3  = (const float*)d_in[16];

  char* ws = (char*)d_ws;
  size_t off = 0;
  auto take = [&](size_t bytes)->char*{
    char* p = ws + off; off += (bytes + 255) & ~(size_t)255; return p; };

  int*   flags  = (int*)  take(256);
  char*  rgn    =         take(58368000);           // slab[4][NN][128] + hacc
  bf16*  slab   = (bf16*) (rgn);
  float* hacc   = (float*)(rgn + 38912000);
  bf16*  meanb  = (bf16*) (rgn);                    // MLP overlays
  bf16*  x1     = (bf16*) (rgn + 15360000);
  bf16*  x2     = (bf16*) (rgn + 30720000);
  bf16*  h1     = (bf16*) take((size_t)NN*HID*2);
  bf16*  h2     = (bf16*) take((size_t)NN*HID*2);
  int*   rowptr = (int*)  take((size_t)(NRD+1)*4);
  int*   cursor = (int*)  take((size_t)NRD*4);      // also deg-count buffer
  int*   csr    = (int*)  take((size_t)RR*EE*4);
  float* ns     = (float*)take((size_t)NRD*4);
  int*   blksum = (int*)  take(8192);
  float* bias   = (float*)take(656*4);
  bf16*  W1p    = (bf16*) take((size_t)2*65536*2);
  bf16*  W2p    = (bf16*) take((size_t)2*65536*2);
  bf16*  Wm1p   = (bf16*) take((size_t)16384*2);
  bf16*  Wm2p   = (bf16*) take((size_t)16384*2);

  if (off > ws_size){
    k_fill<<<(NROWS*NCLS+255)/256, 256, 0, stream>>>(out, NROWS*NCLS, 32.0f);
    return;
  }

  // graph prep: degrees -> scan -> CSR scatter
  k_sniff  <<<1, 64, 0, stream>>>(rmask, ridx, e_src, flags);
  k_init0  <<<(NRD+255)/256, 256, 0, stream>>>(ns /*as cs*/, cursor /*as deg*/);
  k_deg    <<<(RR*EE+255)/256, 256, 0, stream>>>(e_src, e_dst, ns, cursor, flags);
  k_scan1  <<<NBLK, 256, 0, stream>>>(cursor, rowptr, blksum);
  k_scan2  <<<1, 256, 0, stream>>>(blksum);
  k_scan3  <<<(NRD+255)/256, 256, 0, stream>>>(rowptr, blksum, cursor);
  k_scatter<<<(RR*EE+255)/256, 256, 0, stream>>>(e_src, e_dst, cursor, csr, flags);
  k_norm   <<<(NRD+255)/256, 256, 0, stream>>>(ns);
  k_bias   <<<1, 128, 0, stream>>>(b_in, b1, b2, bm1, bm2, bm3, bias);

  k_pack512<<<(4*65536+255)/256, 256, 0, stream>>>(W1, W2, W1p, W2p);
  k_packm  <<<(2*16384+255)/256, 256, 0, stream>>>(Wm1, Wm2, Wm1p, Wm2p);

  // input linear + relu -> h1 (bf16)
  k_gemm_in<<<NN/4, 128, 0, stream>>>(nf, W_in, bias+0, h1);

  int gN = (NN/16 + 3)/4;      // 594 blocks (4 waves each)
  int gR = (NROWS/16 + 3)/4;   // 938

  // RGCN layer 1 (relu): relations 0-3 then 4-7
  k_agg4   <<<4*NN, 128, 0, stream>>>(h1, rowptr, csr, ns, slab, 0);
  k_mfma512<<<gN, 256, 0, stream>>>(slab, W1p,         nullptr, nullptr, hacc, nullptr, 0, 0);
  k_agg4   <<<4*NN, 128, 0, stream>>>(h1, rowptr, csr, ns, slab, 4);
  k_mfma512<<<gN, 256, 0, stream>>>(slab, W1p + 65536, hacc, bias+128, nullptr, h2, 1, 1);

  // RGCN layer 2 (no relu)
  k_agg4   <<<4*NN, 128, 0, stream>>>(h2, rowptr, csr, ns, slab, 0);
  k_mfma512<<<gN, 256, 0, stream>>>(slab, W2p,         nullptr, nullptr, hacc, nullptr, 0, 0);
  k_agg4   <<<4*NN, 128, 0, stream>>>(h2, rowptr, csr, ns, slab, 4);
  k_mfma512<<<gN, 256, 0, stream>>>(slab, W2p + 65536, hacc, bias+256, nullptr, h1, 1, 0);

  // masked mean (graph-phase rgn dead; meanb overlays it)
  k_mean<<<NROWS, 128, 0, stream>>>(h1, ridx, rmask, flags, meanb);

  // MLP head
  k_mfma_out<<<gR, 256, 0, stream>>>(meanb, Wm1p, bias+384, x1, NROWS);
  k_mfma_out<<<gR, 256, 0, stream>>>(x1,    Wm2p, bias+512, x2, NROWS);
  k_last<<<(NROWS*NCLS+255)/256, 256, 0, stream>>>(x2, Wm3, bias+640, out);
}

// Round 17
// 919.775 us; speedup vs baseline: 3.0823x; 1.2341x over previous
//
#include <hip/hip_runtime.h>
#include <hip/hip_bf16.h>

#define NN    38000
#define HID   128
#define RR    8
#define EE    200000
#define NROWS 60000
#define FF    19
#define NCLS  10
#define NRD   (RR*NN)         // 304000
#define NBLK  ((NRD+255)/256) // 1188

typedef __hip_bfloat16 bf16;
typedef __attribute__((ext_vector_type(8))) short short8;
typedef __attribute__((ext_vector_type(4))) float floatx4;

__device__ __forceinline__ float b2f(bf16 x){ return __bfloat162float(x); }
__device__ __forceinline__ bf16  f2b(float x){ return __float2bfloat16(x); }

__device__ __forceinline__ int geti(const void* a, long long i, int wide){
  return wide ? (int)(((const long long*)a)[i]) : ((const int*)a)[i];
}

__global__ void k_fill(float* out, int n, float v){
  int i = blockIdx.x*256 + threadIdx.x;
  if (i < n) out[i] = v;
}

// r12's proven parallel sniff (1 wave)
__global__ void k_sniff(const void* mask, const void* ridx, const void* esrc, int* flags){
  int lane = threadIdx.x;    // blockDim = 64
  const unsigned short* mu = (const unsigned short*)mask;
  int l3f80e=0, l3f80o=0, lbytehi=0, loddnz=0, lother=0;
  for (int i = lane; i < 4096; i += 64){
    unsigned v = mu[i];
    if (v == 0) continue;
    if (v == 0x3F80){ if (i & 1) l3f80o = 1; else l3f80e = 1; continue; }
    unsigned lo = v & 0xFF, hi = v >> 8;
    int lob = (lo == 0 || lo == 1 || lo == 0xFF);
    int hib = (hi == 0 || hi == 1 || hi == 0xFF);
    if (lob && hib){ if (hi) lbytehi = 1; if (i & 1) loddnz = 1; continue; }
    lother = 1;
  }
  int a3f80e = __any(l3f80e);
  int a3f80o = __any(l3f80o);
  int abytehi = __any(lbytehi);
  int aoddnz = __any(loddnz);
  int aother = __any(lother);
  int mtype = -1;
  if (!aother){
    if (a3f80e && !abytehi && !aoddnz)       mtype = 2;
    else if (a3f80o && !a3f80e && !abytehi)  mtype = 3;
    else if (!a3f80e && !a3f80o){
      if (abytehi || aoddnz) mtype = 1;
      else                   mtype = 0;     // int32 0/1 (actual runtime case)
    }
  }
  const int* es = (const int*)esrc;
  int loddE = 0, lseenE = 0;
  for (int i = lane; i < 512; i += 64){
    if (es[2*i+1] != 0) loddE = 1;
    if (es[2*i] > 1)    lseenE = 1;
  }
  int fE = (!__any(loddE) && __any(lseenE)) ? 1 : 0;
  const int* ri = (const int*)ridx;
  int loddI = 0, lseenI = 0;
  for (int i = lane; i < 512; i += 64){
    if (ri[2*i+1] != 0) loddI = 1;
    if (ri[2*i] > 1)    lseenI = 1;
  }
  int fI = (!__any(loddI) && __any(lseenI)) ? 1 : 0;
  if (lane == 0){ flags[1] = mtype; flags[3] = fE; flags[4] = fI; }
}

__global__ void k_init0(float* cs, int* degI){
  int i = blockIdx.x*256 + threadIdx.x;
  if (i >= NRD) return;
  cs[i] = 0.f; degI[i] = 0;
}

__global__ void k_deg(const void* src, const void* dst,
                      float* cs, int* degI, const int* flags){
  int i = blockIdx.x*256 + threadIdx.x;
  if (i >= RR*EE) return;
  int wide = flags[3];
  int r = i / EE;
  int s = geti(src, i, wide);
  int d = geti(dst, i, wide);
  atomicAdd(cs + r*NN + s, 1.0f);
  atomicAdd(degI + r*NN + d, 1);
}

__global__ void k_scan1(const int* degI, int* rowptr, int* blksum){
  __shared__ int ls[256];
  int t = threadIdx.x;
  int i = blockIdx.x*256 + t;
  int v = (i < NRD) ? degI[i] : 0;
  ls[t] = v;
  __syncthreads();
  for (int off = 1; off < 256; off <<= 1){
    int tv = (t >= off) ? ls[t-off] : 0;
    __syncthreads();
    ls[t] += tv;
    __syncthreads();
  }
  if (i < NRD) rowptr[i] = ls[t] - v;
  if (t == 255) blksum[blockIdx.x] = ls[255];
}

__global__ void k_scan2(int* blksum){
  __shared__ int ls[2048];
  int t = threadIdx.x;   // 256
  for (int i = t; i < 2048; i += 256) ls[i] = (i < NBLK) ? blksum[i] : 0;
  __syncthreads();
  for (int off = 1; off < 2048; off <<= 1){
    int tmp[8];
#pragma unroll
    for (int j = 0; j < 8; j++){ int idx = t + j*256; tmp[j] = (idx >= off) ? ls[idx-off] : 0; }
    __syncthreads();
#pragma unroll
    for (int j = 0; j < 8; j++){ int idx = t + j*256; ls[idx] += tmp[j]; }
    __syncthreads();
  }
  for (int i = t; i < NBLK; i += 256) blksum[i] = (i == 0) ? 0 : ls[i-1];
}

__global__ void k_scan3(int* rowptr, const int* blksum, int* cursor){
  int i = blockIdx.x*256 + threadIdx.x;
  if (i >= NRD) return;
  int v = rowptr[i] + blksum[i >> 8];
  rowptr[i] = v;
  cursor[i] = v;
  if (i == 0) rowptr[NRD] = RR*EE;
}

__global__ void k_scatter(const void* src, const void* dst,
                          int* cursor, int* csr, const int* flags){
  int i = blockIdx.x*256 + threadIdx.x;
  if (i >= RR*EE) return;
  int wide = flags[3];
  int r = i / EE;
  int s = geti(src, i, wide);
  int d = geti(dst, i, wide);
  int pos = atomicAdd(cursor + r*NN + d, 1);
  csr[pos] = s;
}

__global__ void k_norm(float* cs){
  int i = blockIdx.x*256 + threadIdx.x;
  if (i >= NRD) return;
  float a = cs[i]; cs[i] = rsqrtf(a > 0.f ? a : 1.f);
}

__global__ void k_bias(const float* b_in, const float* b1, const float* b2,
                       const float* bm1, const float* bm2, const float* bm3, float* o){
  int t = threadIdx.x;
  o[t] = b_in[t];
  float s1 = 0.f, s2 = 0.f;
  for (int r = 0; r < RR; r++){ s1 += b1[r*HID+t]; s2 += b2[r*HID+t]; }
  o[128+t] = s1; o[256+t] = s2;
  o[384+t] = bm1[t]; o[512+t] = bm2[t];
  if (t < NCLS) o[640+t] = bm3[t];
}

// pack BOTH [8][128][128] weight stacks into K=512 MFMA B-frag order
__global__ void k_pack512(const float* __restrict__ WA, const float* __restrict__ WB,
                          bf16* __restrict__ outA, bf16* __restrict__ outB){
  int idx0 = blockIdx.x*256 + threadIdx.x;
  if (idx0 >= 4*65536) return;
  const float* W = (idx0 < 2*65536) ? WA : WB;
  bf16* out      = (idx0 < 2*65536) ? outA : outB;
  int idx = idx0 & (2*65536 - 1);
  int j = idx & 7;
  int l = (idx >> 3) & 63;
  int t = (idx >> 9) & 127;
  int g = idx >> 16;
  int ktg = t & 15, nt = t >> 4;
  int kglob = ktg*32 + ((l>>4)<<3) + j;
  int rel = kglob >> 7;
  int krow = kglob & 127;
  int n = nt*16 + (l&15);
  out[idx] = f2b(W[((g*4 + rel)*128 + krow)*128 + n]);
}

// generic K=KT*32 pack (N=128 cols, NT=8); total = KT*8*512
__global__ void k_packg(const float* __restrict__ B, bf16* __restrict__ out, int KT){
  int idx = blockIdx.x*256 + threadIdx.x;
  if (idx >= KT*4096) return;
  int j  = idx & 7;
  int l  = (idx >> 3) & 63;
  int t  = idx >> 9;
  int kt = t % KT;
  int nt = t / KT;
  int k = kt*32 + ((l>>4)<<3) + j;
  int n = nt*16 + (l&15);
  out[idx] = f2b(B[k*128 + n]);
}

// input linear + relu (f32 VALU, K=64) -> h1 bf16  [r13-r15 proven, restored]
__global__ void k_gemm_in(const float* __restrict__ A, const float* __restrict__ B,
                          const float* bias, bf16* __restrict__ out){
  int row0 = blockIdx.x * 4;
  int col = threadIdx.x;
  float a0=0.f, a1=0.f, a2=0.f, a3=0.f;
  for (int k = 0; k < 64; k++){
    float bv = B[k*HID + col];
    a0 += A[(long long)(row0+0)*64 + k] * bv;
    a1 += A[(long long)(row0+1)*64 + k] * bv;
    a2 += A[(long long)(row0+2)*64 + k] * bv;
    a3 += A[(long long)(row0+3)*64 + k] * bv;
  }
  float bb = bias[col];
  out[(long long)(row0+0)*HID + col] = f2b(fmaxf(a0 + bb, 0.f));
  out[(long long)(row0+1)*HID + col] = f2b(fmaxf(a1 + bb, 0.f));
  out[(long long)(row0+2)*HID + col] = f2b(fmaxf(a2 + bb, 0.f));
  out[(long long)(row0+3)*HID + col] = f2b(fmaxf(a3 + bb, 0.f));
}

// 4 relations' aggregation via CSR; 1 wave/dst, bf16x2 loads (2 feats/lane)
__global__ void k_agg4(const bf16* __restrict__ h, const int* __restrict__ rowptr,
                       const int* __restrict__ csr, const float* __restrict__ ns,
                       bf16* __restrict__ slab, int rbase){
  int b = blockIdx.x;          // 0 .. 4*NN
  int rloc = b / NN;
  int d = b - rloc*NN;
  int r = rbase + rloc;
  int lane = threadIdx.x;      // 0..63
  int rd = r*NN + d;
  int beg = rowptr[rd], end = rowptr[rd+1];
  const unsigned* hv = (const unsigned*)h;
  float acc0 = 0.f, acc1 = 0.f;
  for (int i = beg; i < end; i++){
    int s = csr[i];
    float w = ns[r*NN + s];
    unsigned pv = hv[(long long)s*64 + lane];
    acc0 += w * __uint_as_float(pv << 16);
    acc1 += w * __uint_as_float(pv & 0xffff0000u);
  }
  int deg = end - beg;
  float nd = rsqrtf((float)(deg > 0 ? deg : 1));
  bf16 o0 = f2b(acc0 * nd), o1 = f2b(acc1 * nd);
  unsigned ov = ((unsigned)(*(unsigned short*)&o1) << 16) | (*(unsigned short*)&o0);
  ((unsigned*)slab)[((long long)rloc*NN + d)*64 + lane] = ov;
}

// K=512 MFMA over the [4][NN][128] slab (r14-proven)
__global__ void k_mfma512(const bf16* __restrict__ slab, const bf16* __restrict__ Bp,
                          const float* __restrict__ Cin, const float* __restrict__ bias,
                          float* __restrict__ Cout, bf16* __restrict__ hout,
                          int mode, int relu){
  int wave = (blockIdx.x*blockDim.x + threadIdx.x) >> 6;
  int lane = threadIdx.x & 63;
  int rowBase = wave << 4;
  if (rowBase >= NN) return;
  long long aRow = rowBase + (lane & 15);
  int kGrp = (lane >> 4) << 3;
  floatx4 acc[8];
#pragma unroll
  for (int nt = 0; nt < 8; nt++) acc[nt] = (floatx4){0.f,0.f,0.f,0.f};
  const bf16* bp = Bp + lane*8;
#pragma unroll
  for (int kt = 0; kt < 16; kt++){
    int rel = kt >> 2;
    short8 a = *(const short8*)(slab + ((long long)rel*NN + aRow)*HID + (kt&3)*32 + kGrp);
#pragma unroll
    for (int nt = 0; nt < 8; nt++){
      short8 b = *(const short8*)(bp + (nt*16 + kt)*512);
      acc[nt] = __builtin_amdgcn_mfma_f32_16x16x32_bf16(a, b, acc[nt], 0, 0, 0);
    }
  }
  int colB = lane & 15;
  int rowQ = rowBase + ((lane >> 4) << 2);
  if (mode == 0){
#pragma unroll
    for (int nt = 0; nt < 8; nt++)
#pragma unroll
      for (int v = 0; v < 4; v++)
        Cout[(long long)(rowQ+v)*HID + nt*16 + colB] = acc[nt][v];
  } else {
#pragma unroll
    for (int nt = 0; nt < 8; nt++){
      int col = nt*16 + colB;
      float bb = bias[col];
#pragma unroll
      for (int v = 0; v < 4; v++){
        float x = acc[nt][v] + Cin[(long long)(rowQ+v)*HID + col] + bb;
        if (relu) x = fmaxf(x, 0.f);
        hout[(long long)(rowQ+v)*HID + col] = f2b(x);
      }
    }
  }
}

// K=128 MFMA + relu epilogue (r13-proven layout)
__global__ void k_mfma_out(const bf16* __restrict__ A, const bf16* __restrict__ Bp,
                           const float* __restrict__ bias, bf16* __restrict__ out, int M){
  int wave = (blockIdx.x*blockDim.x + threadIdx.x) >> 6;
  int lane = threadIdx.x & 63;
  int rowBase = wave << 4;
  if (rowBase >= M) return;
  long long aRow = rowBase + (lane & 15);
  int kGrp = (lane >> 4) << 3;
  floatx4 acc[8];
#pragma unroll
  for (int nt = 0; nt < 8; nt++) acc[nt] = (floatx4){0.f,0.f,0.f,0.f};
  const bf16* bp = Bp + lane*8;
#pragma unroll
  for (int kt = 0; kt < 4; kt++){
    short8 a = *(const short8*)(A + aRow*HID + kt*32 + kGrp);
#pragma unroll
    for (int nt = 0; nt < 8; nt++){
      short8 b = *(const short8*)(bp + (nt*4 + kt)*512);
      acc[nt] = __builtin_amdgcn_mfma_f32_16x16x32_bf16(a, b, acc[nt], 0, 0, 0);
    }
  }
  int colB = lane & 15;
  int rowQ = rowBase + ((lane >> 4) << 2);
#pragma unroll
  for (int nt = 0; nt < 8; nt++){
    int col = nt*16 + colB;
    float bb = bias[col];
#pragma unroll
    for (int v = 0; v < 4; v++)
      out[(long long)(rowQ+v)*HID + col] = f2b(fmaxf(acc[nt][v] + bb, 0.f));
  }
}

// masked mean; 1 wave/row, bf16x2 loads; flags-dispatched mask + index width
__global__ void k_mean(const bf16* __restrict__ h, const void* ridx, const void* rmask,
                       const int* flags, bf16* __restrict__ mean){
  int row = blockIdx.x;
  int lane = threadIdx.x;   // 0..63
  int mt = flags[1];
  int wide = flags[4];
  const int* m4            = (const int*)rmask;
  const unsigned char* m1  = (const unsigned char*)rmask;
  const unsigned short* m2 = (const unsigned short*)rmask;
  const unsigned int* mw   = (const unsigned int*)rmask;
  const unsigned* hv = (const unsigned*)h;
  float acc0 = 0.f, acc1 = 0.f, cnt = 0.f;
  for (int j = 0; j < FF; j++){
    int i = row*FF + j;
    int on;
    if      (mt == 1) on = (m1[i] != 0);
    else if (mt == 2) on = (m2[i] != 0);
    else if (mt == 3) on = (mw[i] != 0);
    else              on = (m4[i] != 0);
    if (on){
      int idx = geti(ridx, i, wide);
      unsigned pv = hv[(long long)idx*64 + lane];
      acc0 += __uint_as_float(pv << 16);
      acc1 += __uint_as_float(pv & 0xffff0000u);
      cnt += 1.f;
    }
  }
  float inv = 1.f / fmaxf(cnt, 1.f);
  bf16 o0 = f2b(acc0 * inv), o1 = f2b(acc1 * inv);
  unsigned ov = ((unsigned)(*(unsigned short*)&o1) << 16) | (*(unsigned short*)&o0);
  ((unsigned*)mean)[(long long)row*64 + lane] = ov;
}

// final layer: out(f32)[NROWS][10]
__global__ void k_last(const bf16* __restrict__ A, const float* __restrict__ B,
                       const float* bias, float* __restrict__ out){
  int i = blockIdx.x*256 + threadIdx.x;
  if (i >= NROWS*NCLS) return;
  int row = i / NCLS, col = i - row*NCLS;
  float acc = bias[col];
  const bf16* ar = A + (long long)row*HID;
  for (int k = 0; k < HID; k++) acc += b2f(ar[k]) * B[k*NCLS + col];
  out[i] = acc;
}

extern "C" void kernel_launch(void* const* d_in, const int* in_sizes, int n_in,
                              void* d_out, int out_size, void* d_ws, size_t ws_size,
                              hipStream_t stream){
  float* out = (float*)d_out;

  static const int expect[17] = {
    NN*64, RR*EE, RR*EE, NROWS*FF, NROWS*FF,
    64*HID, HID, RR*HID*HID, RR*HID, RR*HID*HID, RR*HID,
    HID*HID, HID, HID*HID, HID, HID*NCLS, NCLS };
  bool ok = (n_in >= 17) && (out_size == NROWS*NCLS);
  if (ok) for (int i = 0; i < 17; i++) if (in_sizes[i] != expect[i]) { ok = false; break; }
  if (!ok){
    k_fill<<<(NROWS*NCLS+255)/256, 256, 0, stream>>>(out, NROWS*NCLS, 64.0f);
    return;
  }

  const void*  e_src = d_in[1];
  const void*  e_dst = d_in[2];
  const void*  ridx  = d_in[3];
  const void*  rmask = d_in[4];
  const float* nf   = (const float*)d_in[0];
  const float* W_in = (const float*)d_in[5];
  const float* b_in = (const float*)d_in[6];
  const float* W1   = (const float*)d_in[7];
  const float* b1   = (const float*)d_in[8];
  const float* W2   = (const float*)d_in[9];
  const float* b2   = (const float*)d_in[10];
  const float* Wm1  = (const float*)d_in[11];
  const float* bm1  = (const float*)d_in[12];
  const float* Wm2  = (const float*)d_in[13];
  const float* bm2  = (const float*)d_in[14];
  const float* Wm3  = (const float*)d_in[15];
  const float* bm3  = (const float*)d_in[16];

  char* ws = (char*)d_ws;
  size_t off = 0;
  auto take = [&](size_t bytes)->char*{
    char* p = ws + off; off += (bytes + 255) & ~(size_t)255; return p; };

  int*   flags  = (int*)  take(256);
  char*  rgn    =         take(58368000);           // slab[4][NN][128] + hacc
  bf16*  slab   = (bf16*) (rgn);
  float* hacc   = (float*)(rgn + 38912000);
  bf16*  meanb  = (bf16*) (rgn);                    // MLP overlays
  bf16*  x1     = (bf16*) (rgn + 15360000);
  bf16*  x2     = (bf16*) (rgn + 30720000);
  bf16*  h1     = (bf16*) take((size_t)NN*HID*2);
  bf16*  h2     = (bf16*) take((size_t)NN*HID*2);
  int*   rowptr = (int*)  take((size_t)(NRD+1)*4);
  int*   cursor = (int*)  take((size_t)NRD*4);
  int*   csr    = (int*)  take((size_t)RR*EE*4);
  float* ns     = (float*)take((size_t)NRD*4);
  int*   blksum = (int*)  take(8192);
  float* bias   = (float*)take(656*4);
  bf16*  W1p    = (bf16*) take((size_t)2*65536*2);
  bf16*  W2p    = (bf16*) take((size_t)2*65536*2);
  bf16*  Wm1p   = (bf16*) take((size_t)16384*2);
  bf16*  Wm2p   = (bf16*) take((size_t)16384*2);

  if (off > ws_size){
    k_fill<<<(NROWS*NCLS+255)/256, 256, 0, stream>>>(out, NROWS*NCLS, 32.0f);
    return;
  }

  // graph prep: degrees -> scan -> CSR scatter
  k_sniff  <<<1, 64, 0, stream>>>(rmask, ridx, e_src, flags);
  k_init0  <<<(NRD+255)/256, 256, 0, stream>>>(ns, cursor);
  k_deg    <<<(RR*EE+255)/256, 256, 0, stream>>>(e_src, e_dst, ns, cursor, flags);
  k_scan1  <<<NBLK, 256, 0, stream>>>(cursor, rowptr, blksum);
  k_scan2  <<<1, 256, 0, stream>>>(blksum);
  k_scan3  <<<(NRD+255)/256, 256, 0, stream>>>(rowptr, blksum, cursor);
  k_scatter<<<(RR*EE+255)/256, 256, 0, stream>>>(e_src, e_dst, cursor, csr, flags);
  k_norm   <<<(NRD+255)/256, 256, 0, stream>>>(ns);
  k_bias   <<<1, 128, 0, stream>>>(b_in, b1, b2, bm1, bm2, bm3, bias);

  k_pack512<<<(4*65536+255)/256, 256, 0, stream>>>(W1, W2, W1p, W2p);
  k_packg  <<<(4*4096+255)/256, 256, 0, stream>>>(Wm1, Wm1p, 4);
  k_packg  <<<(4*4096+255)/256, 256, 0, stream>>>(Wm2, Wm2p, 4);

  // input linear + relu -> h1 (bf16)  [f32 VALU path, r13-r15 proven]
  k_gemm_in<<<NN/4, 128, 0, stream>>>(nf, W_in, bias+0, h1);

  int gN = (NN/16 + 3)/4;      // 594
  int gR = (NROWS/16 + 3)/4;   // 938

  // RGCN layer 1 (relu): relations 0-3 then 4-7
  k_agg4   <<<4*NN, 64, 0, stream>>>(h1, rowptr, csr, ns, slab, 0);
  k_mfma512<<<gN, 256, 0, stream>>>(slab, W1p,         nullptr, nullptr, hacc, nullptr, 0, 0);
  k_agg4   <<<4*NN, 64, 0, stream>>>(h1, rowptr, csr, ns, slab, 4);
  k_mfma512<<<gN, 256, 0, stream>>>(slab, W1p + 65536, hacc, bias+128, nullptr, h2, 1, 1);

  // RGCN layer 2 (no relu)
  k_agg4   <<<4*NN, 64, 0, stream>>>(h2, rowptr, csr, ns, slab, 0);
  k_mfma512<<<gN, 256, 0, stream>>>(slab, W2p,         nullptr, nullptr, hacc, nullptr, 0, 0);
  k_agg4   <<<4*NN, 64, 0, stream>>>(h2, rowptr, csr, ns, slab, 4);
  k_mfma512<<<gN, 256, 0, stream>>>(slab, W2p + 65536, hacc, bias+256, nullptr, h1, 1, 0);

  // masked mean (graph-phase rgn dead; meanb overlays it)
  k_mean<<<NROWS, 64, 0, stream>>>(h1, ridx, rmask, flags, meanb);

  // MLP head
  k_mfma_out<<<gR, 256, 0, stream>>>(meanb, Wm1p, bias+384, x1, NROWS);
  k_mfma_out<<<gR, 256, 0, stream>>>(x1,    Wm2p, bias+512, x2, NROWS);
  k_last<<<(NROWS*NCLS+255)/256, 256, 0, stream>>>(x2, Wm3, bias+640, out);
}